// Round 7
// baseline (725.458 us; speedup 1.0000x reference)
//
#include <hip/hip_runtime.h>
#include <cstdint>
#include <cstddef>

typedef unsigned char  u8;
typedef unsigned short u16;
typedef unsigned int   u32;

typedef __attribute__((ext_vector_type(8))) short s16x8;
typedef __attribute__((ext_vector_type(4))) short s16x4;
typedef __attribute__((ext_vector_type(4))) float f32x4;
typedef __attribute__((ext_vector_type(4))) u32   u32x4;

#define NTILE 4096   // 262144 / 64 rows per tile

// LDS: EQ 32KB + WK 32KB + WB 16KB = 80KB -> 2 blocks/CU
#define EQ_R 0
#define WK_R 32768
#define WB_O 65536
#define SMEM_BYTES 81920

// ---------------- workspace layout (bytes), total ~19.8 MB ----------------
static const size_t PA_OFF   = 0;          // f32 [4096 tile][512 f] sums
static const size_t PB_OFF   = 8388608;    // f32 [4096][512] sumsq
static const size_t QA_OFF   = 16777216;   // f32 [512 g][512 f] stage-1 sums
static const size_t QB_OFF   = 17825792;   // f32 [512][512]
static const size_t MU_OFF   = 18874368;   // f32 [512]
static const size_t RSTD_OFF = 18876416;   // f32 [512]
static const size_t B1E_OFF  = 18878464;   // f32 [256]
static const size_t WEMB_OFF = 18880512;   // bf16 [3][256][32]
static const size_t WV_OFF   = 18929664;   // bf16 [256][256]
static const size_t W2_OFF   = 19060736;   // bf16 [128][256]
static const size_t W1S_OFF  = 19126272;   // bf16 [256][512] BN-folded
static const size_t WU_OFF   = 19388416;   // f32 [256][256]  Wu = Wq^T Wk
static const size_t G_OFF    = 19650560;   // f32 [2][256][13]
static const size_t GG_OFF   = 19677184;   // f32 [2][256]
static const size_t SCP_OFF  = 19679232;   // f32 [2][256] score params
static const size_t WROW_OFF = 19681280;   // f32 [262144] softmax w1 per row
// end = 20729856

__device__ __forceinline__ u16 f2bf(float f) {
  u32 u = __builtin_bit_cast(u32, f);
  u += 0x7FFFu + ((u >> 16) & 1u);     // RNE
  return (u16)(u >> 16);
}
__device__ __forceinline__ float bf2f(u16 h) {
  u32 u = ((u32)h) << 16;
  return __builtin_bit_cast(float, u);
}

// ---------------- K0: convert weights to bf16 ----------------
__global__ void k0_convert(const float* __restrict__ We,  const float* __restrict__ Wk1,
                           const float* __restrict__ Wk2, const float* __restrict__ Wv,
                           const float* __restrict__ W2,
                           u16* __restrict__ wEmb, u16* __restrict__ wV, u16* __restrict__ wW2)
{
  int i = blockIdx.x * 256 + threadIdx.x;
  if (i < 24576) {                          // padded embeds [agent][h][32]
    int which = i >> 13, rem = i & 8191, h = rem >> 5, c = rem & 31;
    const float* W = (which == 0) ? We : (which == 1) ? Wk1 : Wk2;
    wEmb[i] = (c < 13) ? f2bf(W[h*13 + c]) : (u16)0;
  } else if (i < 24576 + 65536) {           // Wv
    int j = i - 24576;
    wV[j] = f2bf(Wv[j]);
  } else if (i < 24576 + 65536 + 32768) {   // W2
    int j = i - 90112;
    wW2[j] = f2bf(W2[j]);
  }
}

// s_j = e_q^T Wq^T Wk e_kj ; Wu[a][b] = sum_h Wq[h][a] Wk[h][b]
__global__ void k0b_wu(const float* __restrict__ Wq, const float* __restrict__ Wk,
                       float* __restrict__ Wu)
{
  int a = blockIdx.x, b = threadIdx.x;
  float acc = 0.f;
  #pragma unroll 4
  for (int h = 0; h < 256; ++h)
    acc += Wq[h*256 + a] * Wk[h*256 + b];
  Wu[a*256 + b] = acc;
}

__global__ void k0c_G(const float* __restrict__ Wu,
                      const float* __restrict__ Wk1, const float* __restrict__ bk1,
                      const float* __restrict__ Wk2, const float* __restrict__ bk2,
                      float* __restrict__ G, float* __restrict__ g)
{
  int j = blockIdx.x, a = threadIdx.x;
  const float* Wkj = j ? Wk2 : Wk1;
  const float* bkj = j ? bk2 : bk1;
  float acc[13];
  #pragma unroll
  for (int q = 0; q < 13; ++q) acc[q] = 0.f;
  float ga = 0.f;
  for (int b = 0; b < 256; ++b) {
    float wu = Wu[a*256 + b];
    #pragma unroll
    for (int q = 0; q < 13; ++q) acc[q] += wu * Wkj[b*13 + q];
    ga += wu * bkj[b];
  }
  #pragma unroll
  for (int q = 0; q < 13; ++q) G[j*3328 + a*13 + q] = acc[q];
  g[j*256 + a] = ga;
}

__global__ void k0d_M(const float* __restrict__ We, const float* __restrict__ be,
                      const float* __restrict__ G, const float* __restrict__ g,
                      float* __restrict__ scp)
{
  int j = blockIdx.x, t = threadIdx.x;
  float acc = 0.f;
  if (t < 169) {
    int p = t / 13, q = t - p*13;
    for (int a = 0; a < 256; ++a) acc += We[a*13 + p] * G[j*3328 + a*13 + q];
    scp[j*256 + t] = acc;
  } else if (t < 182) {
    int p = t - 169;
    for (int a = 0; a < 256; ++a) acc += We[a*13 + p] * g[j*256 + a];
    scp[j*256 + t] = acc;
  } else if (t < 195) {
    int q = t - 182;
    for (int a = 0; a < 256; ++a) acc += be[a] * G[j*3328 + a*13 + q];
    scp[j*256 + t] = acc;
  } else if (t == 195) {
    for (int a = 0; a < 256; ++a) acc += be[a] * g[j*256 + a];
    scp[j*256 + 195] = acc;
  }
}

__global__ __launch_bounds__(256) void k0e_scores(const float* __restrict__ x,
                                                  const float* __restrict__ scp,
                                                  float* __restrict__ wrow)
{
  int row = blockIdx.x * 256 + threadIdx.x;
  const float* xr = x + (size_t)row*39;
  float f0[13], f1[13], f2[13];
  #pragma unroll
  for (int p = 0; p < 12; ++p) { f0[p] = xr[p]; f1[p] = xr[12+p]; f2[p] = xr[24+p]; }
  f0[12] = xr[36]; f1[12] = xr[37]; f2[12] = xr[38];

  auto score = [&](const float* __restrict__ P, const float (&fj)[13]) -> float {
    float s = P[195];
    #pragma unroll
    for (int p = 0; p < 13; ++p) {
      float tp = P[169 + p];
      #pragma unroll
      for (int q = 0; q < 13; ++q) tp += P[p*13 + q] * fj[q];
      s += f0[p] * tp;
    }
    #pragma unroll
    for (int q = 0; q < 13; ++q) s += P[182 + q] * fj[q];
    return s;
  };
  float s1 = score(scp, f1);
  float s2 = score(scp + 256, f2);
  wrow[row] = 1.f / (1.f + __expf((s2 - s1) * 0.0625f));   // /sqrt(256)
}

// ---------------- staging: 16KB chunks, 256 threads, issue/write split ----------------
// big chunk: 32 rows x 256 cols bf16 (64B/thread in ld[4])
__device__ __forceinline__ void ld_issue32(const u16* __restrict__ src, int stride,
                                           int t, s16x8* ld)
{
  #pragma unroll
  for (int i = 0; i < 4; ++i) {
    int u = t + i*256;
    int row = u >> 5, cu = u & 31;
    ld[i] = *(const s16x8*)(src + row*stride + cu*8);
  }
}
__device__ __forceinline__ void ld_write32(u8* __restrict__ smem, int t, const s16x8* ld)
{
  #pragma unroll
  for (int i = 0; i < 4; ++i) {
    int u = t + i*256;
    int row = u >> 5, cu = u & 31;
    *(s16x8*)(smem + WB_O + ((row*512 + cu*16) ^ ((row & 7) << 4))) = ld[i];
  }
}
// emb agent chunk: 256 rows x 32 cols (16KB)
__device__ __forceinline__ void lde_issue(const u16* __restrict__ src, int t, s16x8* ld)
{
  #pragma unroll
  for (int i = 0; i < 4; ++i) {
    int u = t + i*256;
    int row = u >> 2, cu = u & 3;
    ld[i] = *(const s16x8*)(src + row*32 + cu*8);
  }
}
__device__ __forceinline__ void lde_write(u8* __restrict__ smem, int t, const s16x8* ld)
{
  #pragma unroll
  for (int i = 0; i < 4; ++i) {
    int u = t + i*256;
    int row = u >> 2, cu = u & 3;
    *(s16x8*)(smem + WB_O + ((row*64 + cu*16) ^ ((row & 3) << 4))) = ld[i];
  }
}

// ---------------- LDS accessors ----------------
__device__ __forceinline__ s16x8 ldsA32(const u8* __restrict__ smem, int row, int ks, int hi) {
  return *(const s16x8*)(smem + WB_O + ((row*512 + ks*64 + hi*16) ^ ((row & 7) << 4)));
}
__device__ __forceinline__ s16x8 ldsAe(const u8* __restrict__ smem, int row, int hi) {
  return *(const s16x8*)(smem + WB_O + ((row*64 + hi*16) ^ ((row & 3) << 4)));
}
__device__ __forceinline__ s16x8 ldsB(const u8* __restrict__ smem, int reg, int col, int ks, int hi) {
  return *(const s16x8*)(smem + reg + ((col*512 + ks*64 + hi*16) ^ ((col & 7) << 4)));
}

__device__ __forceinline__ s16x8 make_bfr(const float* __restrict__ xr, int a, int hi)
{
  s16x8 v = {0,0,0,0,0,0,0,0};
  if (hi == 0) {
    #pragma unroll
    for (int e = 0; e < 8; ++e) v[e] = (short)f2bf(xr[12*a + e]);
  } else if (hi == 1) {
    #pragma unroll
    for (int e = 0; e < 4; ++e) v[e] = (short)f2bf(xr[12*a + 8 + e]);
    v[4] = (short)f2bf(xr[36 + a]);   // action column -> padded slot 12
  }
  return v;
}

// embed GEMM: all 256 feats for own 16 cols (16 m-tiles, K=32)
__device__ __forceinline__ void embed_compute(u8* __restrict__ smem, int reg,
                                              const float* __restrict__ bias, s16x8 b,
                                              int cl, int lr, int hi)
{
  #pragma unroll
  for (int m = 0; m < 16; ++m) {
    f32x4 k4 = {0.f,0.f,0.f,0.f};
    k4 = __builtin_amdgcn_mfma_f32_16x16x32_bf16(ldsAe(smem, m*16 + lr, hi), b, k4, 0, 0, 0);
    f32x4 bb = ((const f32x4*)bias)[m*4 + hi];
    s16x4 p;
    #pragma unroll
    for (int r = 0; r < 4; ++r) p[r] = (short)f2bf(k4[r] + bb[r]);
    *(s16x4*)(smem + reg + ((cl*512 + m*32 + hi*8) ^ ((cl & 7) << 4))) = p;
  }
}

// ---- attention: fills EQ=e_q, WK=atten. Pipeline invariant at each compute(c):
//      WB holds chunk c, ld holds chunk c+1 (loads in flight across barriers).
//      If w1s!=null, exits with WB=W1s(kh0,o0), ld=W1s(kh0,o1).
__device__ __forceinline__ void attn_phase(
    u8* __restrict__ smem, const float* __restrict__ x, int rowbase,
    const u16* __restrict__ wEmb, const float* __restrict__ be,
    const float* __restrict__ bk1, const float* __restrict__ bk2,
    const u16* __restrict__ wV, const float* __restrict__ bv,
    const float* __restrict__ wrow, const u16* __restrict__ w1s,
    int t, int cl, int lr, int hi, s16x8* ld)
{
  const float w1 = wrow[rowbase + cl];
  const float w2 = 1.f - w1;
  const float* xr = x + (size_t)(rowbase + cl)*39;

  lde_issue(wEmb, t, ld);
  s16x8 bfr0 = make_bfr(xr, 0, hi);
  s16x8 bfr1 = make_bfr(xr, 1, hi);
  s16x8 bfr2 = make_bfr(xr, 2, hi);

  lde_write(smem, t, ld);
  lde_issue(wEmb + 8192, t, ld);
  __syncthreads();

  embed_compute(smem, EQ_R, be, bfr0, cl, lr, hi);        // e_q
  __syncthreads();
  lde_write(smem, t, ld);
  lde_issue(wEmb + 16384, t, ld);
  __syncthreads();

  embed_compute(smem, WK_R, bk1, bfr1, cl, lr, hi);       // e_k1
  s16x8 bk1r[8];
  #pragma unroll
  for (int ks = 0; ks < 8; ++ks) bk1r[ks] = ldsB(smem, WK_R, cl, ks, hi);
  __syncthreads();
  lde_write(smem, t, ld);
  ld_issue32(wV, 256, t, ld);
  __syncthreads();

  embed_compute(smem, WK_R, bk2, bfr2, cl, lr, hi);       // e_k2
  s16x8 bk2r[8];
  #pragma unroll
  for (int ks = 0; ks < 8; ++ks) bk2r[ks] = ldsB(smem, WK_R, cl, ks, hi);
  __syncthreads();
  ld_write32(smem, t, ld);
  ld_issue32(wV + 8192, 256, t, ld);
  __syncthreads();

  // V loop: 8 chunks of 32 out-feats; atten streams to WK (own cols)
  #pragma unroll
  for (int c = 0; c < 8; ++c) {
    f32x4 a1[2], a2[2];
    #pragma unroll
    for (int m = 0; m < 2; ++m) { a1[m] = {0.f,0.f,0.f,0.f}; a2[m] = {0.f,0.f,0.f,0.f}; }
    #pragma unroll
    for (int ks = 0; ks < 8; ++ks) {
      #pragma unroll
      for (int m = 0; m < 2; ++m) {
        s16x8 a = ldsA32(smem, m*16 + lr, ks, hi);
        a1[m] = __builtin_amdgcn_mfma_f32_16x16x32_bf16(a, bk1r[ks], a1[m], 0, 0, 0);
        a2[m] = __builtin_amdgcn_mfma_f32_16x16x32_bf16(a, bk2r[ks], a2[m], 0, 0, 0);
      }
    }
    #pragma unroll
    for (int m = 0; m < 2; ++m) {
      f32x4 bb = ((const f32x4*)bv)[c*8 + m*4 + hi];
      s16x4 p;
      #pragma unroll
      for (int r = 0; r < 4; ++r) {
        float va = a1[m][r] + bb[r]; va = (va > 0.f) ? va : 0.01f*va;
        float vb = a2[m][r] + bb[r]; vb = (vb > 0.f) ? vb : 0.01f*vb;
        p[r] = (short)f2bf(w1*va + w2*vb);
      }
      *(s16x4*)(smem + WK_R + ((cl*512 + c*64 + m*32 + hi*8) ^ ((cl & 7) << 4))) = p;
    }
    __syncthreads();
    if (c < 7) {
      ld_write32(smem, t, ld);
      if (c < 6)        ld_issue32(wV + (c+2)*8192, 256, t, ld);
      else if (w1s)     ld_issue32(w1s, 512, t, ld);
      __syncthreads();
    } else if (w1s) {
      ld_write32(smem, t, ld);                 // W1s kh0 o0
      ld_issue32(w1s + 16384, 512, t, ld);     // W1s kh0 o1
      __syncthreads();
    }
  }
}

// ---------------- K1: attention pass -> BN partial sums ----------------
__global__ __launch_bounds__(256, 1) void k1_attn(
    const float* __restrict__ x,
    const u16* __restrict__ wEmb, const float* __restrict__ be,
    const float* __restrict__ bk1, const float* __restrict__ bk2,
    const u16* __restrict__ wV, const float* __restrict__ bv,
    const float* __restrict__ wrow,
    float* __restrict__ pA, float* __restrict__ pB)
{
  __shared__ __align__(16) u8 smem[SMEM_BYTES];
  const int t = threadIdx.x;
  const int wt = blockIdx.x;
  const int rowbase = wt * 64;
  const int lane = t & 63;
  const int lr = lane & 15, hi = lane >> 4;
  const int cl = (t >> 6)*16 + lr;
  s16x8 ld[4];

  attn_phase(smem, x, rowbase, wEmb, be, bk1, bk2, wV, bv, wrow, nullptr,
             t, cl, lr, hi, ld);

  // stats: thread t owns feature t (EQ) and 256+t (WK)
  float s0 = 0.f, q0 = 0.f, s1 = 0.f, q1 = 0.f;
  for (int r = 0; r < 64; ++r) {
    int off = (r*512 + t*2) ^ ((r & 7) << 4);
    float a = bf2f(*(const u16*)(smem + EQ_R + off));
    float b = bf2f(*(const u16*)(smem + WK_R + off));
    s0 += a; q0 += a*a; s1 += b; q1 += b*b;
  }
  pA[(size_t)wt*512 + t]       = s0;
  pA[(size_t)wt*512 + 256 + t] = s1;
  pB[(size_t)wt*512 + t]       = q0;
  pB[(size_t)wt*512 + 256 + t] = q1;
}

// ---------------- KR1: stage-1 reduce: 4096 tiles -> 512 groups ----------------
__global__ void kR1_reduce(const float* __restrict__ pA, const float* __restrict__ pB,
                           float* __restrict__ qA, float* __restrict__ qB)
{
  int g = blockIdx.x, t = threadIdx.x;   // 512 x 256
  float2 sA = make_float2(0.f, 0.f), sB = make_float2(0.f, 0.f);
  #pragma unroll
  for (int k = 0; k < 8; ++k) {
    size_t wg = (size_t)g*8 + k;
    float2 a = *(const float2*)(pA + wg*512 + 2*t);
    float2 b = *(const float2*)(pB + wg*512 + 2*t);
    sA.x += a.x; sA.y += a.y; sB.x += b.x; sB.y += b.y;
  }
  *(float2*)(qA + (size_t)g*512 + 2*t) = sA;
  *(float2*)(qB + (size_t)g*512 + 2*t) = sB;
}

// ---------------- KR2: final reduce -> mu, rstd ----------------
__global__ void kR2_stats(const float* __restrict__ qA, const float* __restrict__ qB,
                          float* __restrict__ mu, float* __restrict__ rstd)
{
  int f = blockIdx.x, t = threadIdx.x;   // 512 blocks x 256 threads
  float s = 0.f, q = 0.f;
  #pragma unroll
  for (int k = 0; k < 2; ++k) {
    int g = t + k*256;
    s += qA[(size_t)g*512 + f];
    q += qB[(size_t)g*512 + f];
  }
  #pragma unroll
  for (int off = 1; off < 64; off <<= 1) {
    s += __shfl_xor(s, off);
    q += __shfl_xor(q, off);
  }
  __shared__ float ls[4], lq[4];
  if ((t & 63) == 0) { ls[t >> 6] = s; lq[t >> 6] = q; }
  __syncthreads();
  if (t == 0) {
    float S = ls[0]+ls[1]+ls[2]+ls[3];
    float Q = lq[0]+lq[1]+lq[2]+lq[3];
    float m = S * (1.f/262144.f);
    float v = Q * (1.f/262144.f) - m*m;   // biased variance
    mu[f] = m;
    rstd[f] = 1.f / sqrtf(v + 1e-5f);
  }
}

// ---------------- K2b: fold BN into W1 ----------------
__global__ void k2b_fold(const float* __restrict__ W1, const float* __restrict__ b1,
                         const float* __restrict__ mu, const float* __restrict__ rstd,
                         u16* __restrict__ W1s, float* __restrict__ b1eff)
{
  int o = blockIdx.x, t = threadIdx.x;   // 256 blocks x 256 threads
  float local = 0.f;
  #pragma unroll
  for (int k = 0; k < 2; ++k) {
    int f = t + k*256;
    float w = W1[o*512 + f];
    float r = rstd[f];
    W1s[o*512 + f] = f2bf(w * r);
    local += w * r * mu[f];
  }
  #pragma unroll
  for (int off = 1; off < 64; off <<= 1) local += __shfl_xor(local, off);
  __shared__ float ls[4];
  if ((t & 63) == 0) ls[t >> 6] = local;
  __syncthreads();
  if (t == 0) b1eff[o] = b1[o] - (ls[0]+ls[1]+ls[2]+ls[3]);
}

// ---------------- K3: attention recompute + MLP head ----------------
__global__ __launch_bounds__(256, 1) void k3_mlp(
    const float* __restrict__ x,
    const u16* __restrict__ wEmb, const float* __restrict__ be,
    const float* __restrict__ bk1, const float* __restrict__ bk2,
    const u16* __restrict__ wV, const float* __restrict__ bv,
    const float* __restrict__ wrow,
    const u16* __restrict__ W1s, const float* __restrict__ b1eff,
    const u16* __restrict__ wW2, const float* __restrict__ b2,
    const float* __restrict__ W3, const float* __restrict__ b3,
    float* __restrict__ out)
{
  __shared__ __align__(16) u8 smem[SMEM_BYTES];
  const int t = threadIdx.x;
  const int wt = blockIdx.x;
  const int rowbase = wt * 64;
  const int lane = t & 63;
  const int lr = lane & 15, hi = lane >> 4;
  const int cl = (t >> 6)*16 + lr;
  s16x8 ld[4];

  attn_phase(smem, x, rowbase, wEmb, be, bk1, bk2, wV, bv, wrow, W1s,
             t, cl, lr, hi, ld);
  // invariant: WB = W1s(kh0,o0), ld = W1s(kh0,o1)

  f32x4 acc[16];
  #pragma unroll
  for (int j = 0; j < 16; ++j) acc[j] = {0.f,0.f,0.f,0.f};
  s16x8 bkr[8];

  // GEMM1 kh=0: B = e_q (EQ), 8 chunks of 32 out-feats
  #pragma unroll
  for (int ks = 0; ks < 8; ++ks) bkr[ks] = ldsB(smem, EQ_R, cl, ks, hi);
  #pragma unroll
  for (int c = 0; c < 8; ++c) {
    #pragma unroll
    for (int ks = 0; ks < 8; ++ks)
      #pragma unroll
      for (int m = 0; m < 2; ++m)
        acc[c*2+m] = __builtin_amdgcn_mfma_f32_16x16x32_bf16(
            ldsA32(smem, m*16 + lr, ks, hi), bkr[ks], acc[c*2+m], 0, 0, 0);
    __syncthreads();
    ld_write32(smem, t, ld);
    const u16* nxt = (c < 6) ? (W1s + (size_t)(c+2)*16384)
                             : (W1s + 256 + (size_t)(c-6)*16384);
    ld_issue32(nxt, 512, t, ld);
    __syncthreads();
  }

  // GEMM1 kh=1: B = atten (WK)
  #pragma unroll
  for (int ks = 0; ks < 8; ++ks) bkr[ks] = ldsB(smem, WK_R, cl, ks, hi);
  #pragma unroll
  for (int c = 0; c < 8; ++c) {
    #pragma unroll
    for (int ks = 0; ks < 8; ++ks)
      #pragma unroll
      for (int m = 0; m < 2; ++m)
        acc[c*2+m] = __builtin_amdgcn_mfma_f32_16x16x32_bf16(
            ldsA32(smem, m*16 + lr, ks, hi), bkr[ks], acc[c*2+m], 0, 0, 0);
    __syncthreads();
    ld_write32(smem, t, ld);
    const u16* nxt = (c < 6) ? (W1s + 256 + (size_t)(c+2)*16384)
                             : (wW2 + (size_t)(c-6)*8192);
    ld_issue32(nxt, (c < 6) ? 512 : 256, t, ld);
    __syncthreads();
  }
  // invariant: WB = W2 c0, ld = W2 c1

  // h1 -> EQ (own cols; EQ only ever read by owning wave)
  #pragma unroll
  for (int j = 0; j < 16; ++j) {
    f32x4 bb = ((const f32x4*)b1eff)[j*4 + hi];
    s16x4 p;
    #pragma unroll
    for (int r = 0; r < 4; ++r) {
      float v = acc[j][r] + bb[r];
      p[r] = (short)f2bf((v > 0.f) ? v : 0.f);
    }
    *(s16x4*)(smem + EQ_R + ((cl*512 + j*32 + hi*8) ^ ((cl & 7) << 4))) = p;
  }

  // GEMM2: B = h1 (EQ), 4 chunks of 32 out-feats
  f32x4 acc2[8];
  #pragma unroll
  for (int j = 0; j < 8; ++j) acc2[j] = {0.f,0.f,0.f,0.f};
  #pragma unroll
  for (int ks = 0; ks < 8; ++ks) bkr[ks] = ldsB(smem, EQ_R, cl, ks, hi);
  #pragma unroll
  for (int c = 0; c < 4; ++c) {
    #pragma unroll
    for (int ks = 0; ks < 8; ++ks)
      #pragma unroll
      for (int m = 0; m < 2; ++m)
        acc2[c*2+m] = __builtin_amdgcn_mfma_f32_16x16x32_bf16(
            ldsA32(smem, m*16 + lr, ks, hi), bkr[ks], acc2[c*2+m], 0, 0, 0);
    __syncthreads();
    if (c < 3) {
      ld_write32(smem, t, ld);
      if (c < 2) ld_issue32(wW2 + (size_t)(c+2)*8192, 256, t, ld);
      __syncthreads();
    }
  }

  // h2 -> WK bytes 0..255 (own cols)
  #pragma unroll
  for (int j = 0; j < 8; ++j) {
    f32x4 bb = ((const f32x4*)b2)[j*4 + hi];
    s16x4 p;
    #pragma unroll
    for (int r = 0; r < 4; ++r) {
      float v = acc2[j][r] + bb[r];
      p[r] = (short)f2bf((v > 0.f) ? v : 0.f);
    }
    *(s16x4*)(smem + WK_R + ((cl*512 + j*32 + hi*8) ^ ((cl & 7) << 4))) = p;
  }
  __syncthreads();

  // out = W3 . h2 + b3 (one thread per row)
  if (t < 64) {
    float s = b3[0];
    #pragma unroll
    for (int jj = 0; jj < 16; ++jj) {
      const u32x4 v = *(const u32x4*)(smem + WK_R + ((t*512 + jj*16) ^ ((t & 7) << 4)));
      #pragma unroll
      for (int q2 = 0; q2 < 4; ++q2) {
        u32 u = v[q2];
        s += bf2f((u16)(u & 0xFFFFu)) * W3[jj*8 + q2*2];
        s += bf2f((u16)(u >> 16))     * W3[jj*8 + q2*2 + 1];
      }
    }
    out[rowbase + t] = s;
  }
}

extern "C" void kernel_launch(void* const* d_in, const int* in_sizes, int n_in,
                              void* d_out, int out_size, void* d_ws, size_t ws_size,
                              hipStream_t stream)
{
  const float* x   = (const float*)d_in[0];
  const float* We  = (const float*)d_in[1];
  const float* be  = (const float*)d_in[2];
  const float* Wk1 = (const float*)d_in[3];
  const float* bk1 = (const float*)d_in[4];
  const float* Wk2 = (const float*)d_in[5];
  const float* bk2 = (const float*)d_in[6];
  const float* Wq  = (const float*)d_in[7];
  const float* Wk  = (const float*)d_in[8];
  const float* Wv  = (const float*)d_in[9];
  const float* bv  = (const float*)d_in[10];
  const float* W1  = (const float*)d_in[11];
  const float* b1  = (const float*)d_in[12];
  const float* W2  = (const float*)d_in[13];
  const float* b2  = (const float*)d_in[14];
  const float* W3  = (const float*)d_in[15];
  const float* b3  = (const float*)d_in[16];

  u8* ws = (u8*)d_ws;
  float* pA    = (float*)(ws + PA_OFF);
  float* pB    = (float*)(ws + PB_OFF);
  float* qA    = (float*)(ws + QA_OFF);
  float* qB    = (float*)(ws + QB_OFF);
  float* mu    = (float*)(ws + MU_OFF);
  float* rstd  = (float*)(ws + RSTD_OFF);
  float* b1eff = (float*)(ws + B1E_OFF);
  u16*   wEmb  = (u16*)(ws + WEMB_OFF);
  u16*   wVb   = (u16*)(ws + WV_OFF);
  u16*   wW2   = (u16*)(ws + W2_OFF);
  u16*   wW1s  = (u16*)(ws + W1S_OFF);
  float* Wu    = (float*)(ws + WU_OFF);
  float* G     = (float*)(ws + G_OFF);
  float* g     = (float*)(ws + GG_OFF);
  float* scp   = (float*)(ws + SCP_OFF);
  float* wrow  = (float*)(ws + WROW_OFF);

  k0_convert<<<dim3(480), dim3(256), 0, stream>>>(We, Wk1, Wk2, Wv, W2, wEmb, wVb, wW2);
  k0b_wu<<<dim3(256), dim3(256), 0, stream>>>(Wq, Wk, Wu);
  k0c_G<<<dim3(2), dim3(256), 0, stream>>>(Wu, Wk1, bk1, Wk2, bk2, G, g);
  k0d_M<<<dim3(2), dim3(256), 0, stream>>>(We, be, G, g, scp);
  k0e_scores<<<dim3(1024), dim3(256), 0, stream>>>(x, scp, wrow);
  k1_attn<<<dim3(NTILE), dim3(256), 0, stream>>>(x, wEmb, be, bk1, bk2, wVb, bv, wrow, pA, pB);
  kR1_reduce<<<dim3(512), dim3(256), 0, stream>>>(pA, pB, qA, qB);
  kR2_stats<<<dim3(512), dim3(256), 0, stream>>>(qA, qB, mu, rstd);
  k2b_fold<<<dim3(256), dim3(256), 0, stream>>>(W1, b1, mu, rstd, wW1s, b1eff);
  k3_mlp<<<dim3(NTILE), dim3(256), 0, stream>>>(x, wEmb, be, bk1, bk2, wVb, bv, wrow,
                                                wW1s, b1eff, wW2, b2, W3, b3,
                                                (float*)d_out);
}

// Round 8
// 544.204 us; speedup vs baseline: 1.3331x; 1.3331x over previous
//
#include <hip/hip_runtime.h>
#include <cstdint>
#include <cstddef>

typedef unsigned char  u8;
typedef unsigned short u16;
typedef unsigned int   u32;

typedef __attribute__((ext_vector_type(8))) short s16x8;
typedef __attribute__((ext_vector_type(4))) short s16x4;
typedef __attribute__((ext_vector_type(4))) float f32x4;
typedef __attribute__((ext_vector_type(4))) u32   u32x4;

#define NTILE 4096   // 262144 / 64 rows per tile

// LDS: ACT_EQ 33KB + ACT_WK 33KB + WB double buffer 2x33KB = 132KB
#define ACT_EQ 0
#define ACT_WK 33792
#define WB0    67584
#define WBSZ   33792
#define SMEM_BYTES 135168
#define WBo(p) (WB0 + (p)*WBSZ)

#define MFMA __builtin_amdgcn_mfma_f32_16x16x32_bf16

// raw barrier: LDS visibility without draining vmem (T3/T4; m201 template)
#define BARX() do { __builtin_amdgcn_sched_barrier(0); \
  asm volatile("s_waitcnt lgkmcnt(0)"); \
  __builtin_amdgcn_s_barrier(); \
  __builtin_amdgcn_sched_barrier(0); } while (0)

// ---------------- workspace layout (bytes), total ~19.8 MB ----------------
static const size_t PA_OFF   = 0;          // f32 [4096 tile][512 f] sums
static const size_t PB_OFF   = 8388608;    // f32 [4096][512] sumsq
static const size_t QA_OFF   = 16777216;   // f32 [512 g][512 f] stage-1 sums
static const size_t QB_OFF   = 17825792;   // f32 [512][512]
static const size_t MU_OFF   = 18874368;   // f32 [512]
static const size_t RSTD_OFF = 18876416;   // f32 [512]
static const size_t B1E_OFF  = 18878464;   // f32 [256]
static const size_t WEMB_OFF = 18880512;   // bf16 [3][256][32]
static const size_t WV_OFF   = 18929664;   // bf16 [256][256]
static const size_t W2_OFF   = 19060736;   // bf16 [128][256]
static const size_t W1S_OFF  = 19126272;   // bf16 [256][512] BN-folded
static const size_t WU_OFF   = 19388416;   // f32 [256][256]  Wu = Wq^T Wk
static const size_t G_OFF    = 19650560;   // f32 [2][256][13]
static const size_t GG_OFF   = 19677184;   // f32 [2][256]
static const size_t SCP_OFF  = 19679232;   // f32 [2][256] score params
static const size_t WROW_OFF = 19681280;   // f32 [262144] softmax w1 per row
// end = 20729856

__device__ __forceinline__ u16 f2bf(float f) {
  u32 u = __builtin_bit_cast(u32, f);
  u += 0x7FFFu + ((u >> 16) & 1u);     // RNE
  return (u16)(u >> 16);
}
__device__ __forceinline__ float bf2f(u16 h) {
  u32 u = ((u32)h) << 16;
  return __builtin_bit_cast(float, u);
}

// ---------------- K0: convert weights to bf16 ----------------
__global__ void k0_convert(const float* __restrict__ We,  const float* __restrict__ Wk1,
                           const float* __restrict__ Wk2, const float* __restrict__ Wv,
                           const float* __restrict__ W2,
                           u16* __restrict__ wEmb, u16* __restrict__ wV, u16* __restrict__ wW2)
{
  int i = blockIdx.x * 256 + threadIdx.x;
  if (i < 24576) {                          // padded embeds [agent][h][32]
    int which = i >> 13, rem = i & 8191, h = rem >> 5, c = rem & 31;
    const float* W = (which == 0) ? We : (which == 1) ? Wk1 : Wk2;
    wEmb[i] = (c < 13) ? f2bf(W[h*13 + c]) : (u16)0;
  } else if (i < 24576 + 65536) {           // Wv
    int j = i - 24576;
    wV[j] = f2bf(Wv[j]);
  } else if (i < 24576 + 65536 + 32768) {   // W2
    int j = i - 90112;
    wW2[j] = f2bf(W2[j]);
  }
}

// s_j = e_q^T Wq^T Wk e_kj ; Wu[a][b] = sum_h Wq[h][a] Wk[h][b]
__global__ void k0b_wu(const float* __restrict__ Wq, const float* __restrict__ Wk,
                       float* __restrict__ Wu)
{
  int a = blockIdx.x, b = threadIdx.x;
  float acc = 0.f;
  #pragma unroll 4
  for (int h = 0; h < 256; ++h)
    acc += Wq[h*256 + a] * Wk[h*256 + b];
  Wu[a*256 + b] = acc;
}

__global__ void k0c_G(const float* __restrict__ Wu,
                      const float* __restrict__ Wk1, const float* __restrict__ bk1,
                      const float* __restrict__ Wk2, const float* __restrict__ bk2,
                      float* __restrict__ G, float* __restrict__ g)
{
  int j = blockIdx.x, a = threadIdx.x;
  const float* Wkj = j ? Wk2 : Wk1;
  const float* bkj = j ? bk2 : bk1;
  float acc[13];
  #pragma unroll
  for (int q = 0; q < 13; ++q) acc[q] = 0.f;
  float ga = 0.f;
  for (int b = 0; b < 256; ++b) {
    float wu = Wu[a*256 + b];
    #pragma unroll
    for (int q = 0; q < 13; ++q) acc[q] += wu * Wkj[b*13 + q];
    ga += wu * bkj[b];
  }
  #pragma unroll
  for (int q = 0; q < 13; ++q) G[j*3328 + a*13 + q] = acc[q];
  g[j*256 + a] = ga;
}

__global__ void k0d_M(const float* __restrict__ We, const float* __restrict__ be,
                      const float* __restrict__ G, const float* __restrict__ g,
                      float* __restrict__ scp)
{
  int j = blockIdx.x, t = threadIdx.x;
  float acc = 0.f;
  if (t < 169) {
    int p = t / 13, q = t - p*13;
    for (int a = 0; a < 256; ++a) acc += We[a*13 + p] * G[j*3328 + a*13 + q];
    scp[j*256 + t] = acc;
  } else if (t < 182) {
    int p = t - 169;
    for (int a = 0; a < 256; ++a) acc += We[a*13 + p] * g[j*256 + a];
    scp[j*256 + t] = acc;
  } else if (t < 195) {
    int q = t - 182;
    for (int a = 0; a < 256; ++a) acc += be[a] * G[j*3328 + a*13 + q];
    scp[j*256 + t] = acc;
  } else if (t == 195) {
    for (int a = 0; a < 256; ++a) acc += be[a] * g[j*256 + a];
    scp[j*256 + 195] = acc;
  }
}

__global__ __launch_bounds__(256) void k0e_scores(const float* __restrict__ x,
                                                  const float* __restrict__ scp,
                                                  float* __restrict__ wrow)
{
  int row = blockIdx.x * 256 + threadIdx.x;
  const float* xr = x + (size_t)row*39;
  float f0[13], f1[13], f2[13];
  #pragma unroll
  for (int p = 0; p < 12; ++p) { f0[p] = xr[p]; f1[p] = xr[12+p]; f2[p] = xr[24+p]; }
  f0[12] = xr[36]; f1[12] = xr[37]; f2[12] = xr[38];

  auto score = [&](const float* __restrict__ P, const float (&fj)[13]) -> float {
    float s = P[195];
    #pragma unroll
    for (int p = 0; p < 13; ++p) {
      float tp = P[169 + p];
      #pragma unroll
      for (int q = 0; q < 13; ++q) tp += P[p*13 + q] * fj[q];
      s += f0[p] * tp;
    }
    #pragma unroll
    for (int q = 0; q < 13; ++q) s += P[182 + q] * fj[q];
    return s;
  };
  float s1 = score(scp, f1);
  float s2 = score(scp + 256, f2);
  wrow[row] = 1.f / (1.f + __expf((s2 - s1) * 0.0625f));   // /sqrt(256)
}

// ---------------- staging helpers (512 threads) ----------------
// weight chunk: 64 rows x 256 cols bf16 -> LDS stride 528 (pad kills bank aliasing)
__device__ __forceinline__ void ldw_issue(const u16* __restrict__ src, int stride,
                                          int t, s16x8* ld)
{
  #pragma unroll
  for (int i = 0; i < 4; ++i) {
    int u = t + i*512;
    ld[i] = *(const s16x8*)(src + (u >> 5)*stride + (u & 31)*8);
  }
}
__device__ __forceinline__ void ldw_write(u8* __restrict__ wb, int t, const s16x8* ld)
{
  #pragma unroll
  for (int i = 0; i < 4; ++i) {
    int u = t + i*512;
    *(s16x8*)(wb + (u >> 5)*528 + (u & 31)*16) = ld[i];
  }
}
// emb chunk: 256 rows x 32 cols bf16 -> LDS stride 80
__device__ __forceinline__ void lde_issue(const u16* __restrict__ src, int t, s16x8* ld)
{
  #pragma unroll
  for (int i = 0; i < 2; ++i) {
    int u = t + i*512;
    ld[i] = *(const s16x8*)(src + (u >> 2)*32 + (u & 3)*8);
  }
}
__device__ __forceinline__ void lde_write(u8* __restrict__ wb, int t, const s16x8* ld)
{
  #pragma unroll
  for (int i = 0; i < 2; ++i) {
    int u = t + i*512;
    *(s16x8*)(wb + (u >> 2)*80 + (u & 3)*16) = ld[i];
  }
}

__device__ __forceinline__ s16x8 make_bfr(const float* __restrict__ xr, int a, int hi)
{
  s16x8 v = {0,0,0,0,0,0,0,0};
  if (hi == 0) {
    #pragma unroll
    for (int e = 0; e < 8; ++e) v[e] = (short)f2bf(xr[12*a + e]);
  } else if (hi == 1) {
    #pragma unroll
    for (int e = 0; e < 4; ++e) v[e] = (short)f2bf(xr[12*a + 8 + e]);
    v[4] = (short)f2bf(xr[36 + a]);   // action column -> padded slot 12
  }
  return v;
}

// embed GEMM: wave (colgV,mgV) computes feats [mgV*128,+128) for its 16 cols
__device__ __forceinline__ void embed_compute(const u8* __restrict__ wb, u8* __restrict__ act,
    const float* __restrict__ bias, s16x8 b, int clV, int lr, int hi, int mgV)
{
  #pragma unroll
  for (int m = 0; m < 8; ++m) {
    int row = mgV*128 + m*16 + lr;
    f32x4 k4 = {0.f, 0.f, 0.f, 0.f};
    k4 = MFMA(*(const s16x8*)(wb + row*80 + hi*16), b, k4, 0, 0, 0);
    f32x4 bb = ((const f32x4*)bias)[mgV*32 + m*4 + hi];
    s16x4 pk;
    #pragma unroll
    for (int r = 0; r < 4; ++r) pk[r] = (short)f2bf(k4[r] + bb[r]);
    *(s16x4*)(act + clV*528 + mgV*256 + m*32 + hi*8) = pk;
  }
}

// ---- shared pipelined phase: e_q -> ACT_EQ, atten -> ACT_WK; returns buffer parity.
// Chunk list: 0=emb0 1=emb1 2=emb2 3..6=V0..V3 [7=n7 8=n8].
// Invariant at compute(i): WB[p]=chunk i, ld=chunk i+1 (loads still in flight OK).
__device__ __forceinline__ int attn_iters(
    u8* __restrict__ smem, const float* __restrict__ x, int rowbase,
    const u16* __restrict__ wEmb, const float* __restrict__ be,
    const float* __restrict__ bk1, const float* __restrict__ bk2,
    const u16* __restrict__ wV, const float* __restrict__ bv,
    const float* __restrict__ wrow,
    const u16* __restrict__ n7, int n7s, const u16* __restrict__ n8, int n8s,
    int t, int lr, int hi, s16x8* ld)
{
  const int wv_ = t >> 6;
  const int colgV = wv_ & 3, mgV = wv_ >> 2;
  const int clV = colgV*16 + lr;
  const float w1 = wrow[rowbase + clV], w2 = 1.f - w1;
  const float* xr = x + (size_t)(rowbase + clV)*39;
  s16x8 bfr0 = make_bfr(xr, 0, hi);
  s16x8 bfr1 = make_bfr(xr, 1, hi);
  s16x8 bfr2 = make_bfr(xr, 2, hi);

  // prologue: chunk0 -> WB0; issue chunk1
  lde_issue(wEmb, t, ld);
  lde_write(smem + WBo(0), t, ld);
  lde_issue(wEmb + 8192, t, ld);
  BARX();
  int p = 0;

  // i0: emb0 -> e_q
  lde_write(smem + WBo(p^1), t, ld);
  lde_issue(wEmb + 16384, t, ld);
  embed_compute(smem + WBo(p), smem + ACT_EQ, be, bfr0, clV, lr, hi, mgV);
  BARX(); p ^= 1;

  // i1: emb1 -> e_k1 ; capture bk1r
  lde_write(smem + WBo(p^1), t, ld);
  ldw_issue(wV, 256, t, ld);
  embed_compute(smem + WBo(p), smem + ACT_WK, bk1, bfr1, clV, lr, hi, mgV);
  BARX();
  s16x8 bk1r[8];
  #pragma unroll
  for (int ks = 0; ks < 8; ++ks)
    bk1r[ks] = *(const s16x8*)(smem + ACT_WK + clV*528 + ks*64 + hi*16);
  BARX(); p ^= 1;

  // i2: emb2 -> e_k2 ; capture bk2r
  ldw_write(smem + WBo(p^1), t, ld);
  ldw_issue(wV + 16384, 256, t, ld);
  embed_compute(smem + WBo(p), smem + ACT_WK, bk2, bfr2, clV, lr, hi, mgV);
  BARX();
  s16x8 bk2r[8];
  #pragma unroll
  for (int ks = 0; ks < 8; ++ks)
    bk2r[ks] = *(const s16x8*)(smem + ACT_WK + clV*528 + ks*64 + hi*16);
  BARX(); p ^= 1;

  // i3..i6: V chunks 0..3 -> atten streamed to ACT_WK (own cols)
  #pragma unroll
  for (int c = 0; c < 4; ++c) {
    if (c < 3)      ldw_write(smem + WBo(p^1), t, ld);   // V1,V2,V3
    else if (n7)    ldw_write(smem + WBo(p^1), t, ld);   // chunk7
    if (c == 0)      ldw_issue(wV + 2*16384, 256, t, ld);
    else if (c == 1) ldw_issue(wV + 3*16384, 256, t, ld);
    else if (c == 2) { if (n7) ldw_issue(n7, n7s, t, ld); }
    else             { if (n8) ldw_issue(n8, n8s, t, ld); }

    f32x4 a1[2], a2[2];
    #pragma unroll
    for (int m = 0; m < 2; ++m) { a1[m] = {0.f,0.f,0.f,0.f}; a2[m] = {0.f,0.f,0.f,0.f}; }
    #pragma unroll
    for (int ks = 0; ks < 8; ++ks) {
      #pragma unroll
      for (int m = 0; m < 2; ++m) {
        s16x8 a = *(const s16x8*)(smem + WBo(p) + (mgV*32 + m*16 + lr)*528 + ks*64 + hi*16);
        a1[m] = MFMA(a, bk1r[ks], a1[m], 0, 0, 0);
        a2[m] = MFMA(a, bk2r[ks], a2[m], 0, 0, 0);
      }
    }
    #pragma unroll
    for (int m = 0; m < 2; ++m) {
      f32x4 bb = ((const f32x4*)bv)[c*16 + mgV*8 + m*4 + hi];
      s16x4 pk;
      #pragma unroll
      for (int r = 0; r < 4; ++r) {
        float va = a1[m][r] + bb[r]; va = (va > 0.f) ? va : 0.01f*va;
        float vb = a2[m][r] + bb[r]; vb = (vb > 0.f) ? vb : 0.01f*vb;
        pk[r] = (short)f2bf(w1*va + w2*vb);
      }
      *(s16x4*)(smem + ACT_WK + clV*528 + c*128 + mgV*64 + m*32 + hi*8) = pk;
    }
    BARX(); p ^= 1;
  }
  return p;
}

// ---------------- K1: attention pass -> BN partial sums ----------------
__global__ __launch_bounds__(512) __attribute__((amdgpu_waves_per_eu(1, 2)))
void k1_attn(
    const float* __restrict__ x,
    const u16* __restrict__ wEmb, const float* __restrict__ be,
    const float* __restrict__ bk1, const float* __restrict__ bk2,
    const u16* __restrict__ wV, const float* __restrict__ bv,
    const float* __restrict__ wrow,
    float* __restrict__ pA, float* __restrict__ pB)
{
  __shared__ __align__(16) u8 smem[SMEM_BYTES];
  const int t = threadIdx.x;
  const int wt = blockIdx.x;
  const int rowbase = wt * 64;
  const int lane = t & 63;
  const int lr = lane & 15, hi = lane >> 4;
  s16x8 ld[4];

  attn_iters(smem, x, rowbase, wEmb, be, bk1, bk2, wV, bv, wrow,
             nullptr, 0, nullptr, 0, t, lr, hi, ld);

  // stats: thread t owns global feature t (t<256: e_q, else atten)
  const int fl = t & 255;
  const u8* base = smem + ((t < 256) ? ACT_EQ : ACT_WK);
  float s = 0.f, q = 0.f;
  for (int r = 0; r < 64; ++r) {
    float a = bf2f(*(const u16*)(base + r*528 + fl*2));
    s += a; q += a*a;
  }
  pA[(size_t)wt*512 + t] = s;
  pB[(size_t)wt*512 + t] = q;
}

// ---------------- KR1: stage-1 reduce: 4096 tiles -> 512 groups ----------------
__global__ void kR1_reduce(const float* __restrict__ pA, const float* __restrict__ pB,
                           float* __restrict__ qA, float* __restrict__ qB)
{
  int g = blockIdx.x, t = threadIdx.x;   // 512 x 256
  float2 sA = make_float2(0.f, 0.f), sB = make_float2(0.f, 0.f);
  #pragma unroll
  for (int k = 0; k < 8; ++k) {
    size_t wg = (size_t)g*8 + k;
    float2 a = *(const float2*)(pA + wg*512 + 2*t);
    float2 b = *(const float2*)(pB + wg*512 + 2*t);
    sA.x += a.x; sA.y += a.y; sB.x += b.x; sB.y += b.y;
  }
  *(float2*)(qA + (size_t)g*512 + 2*t) = sA;
  *(float2*)(qB + (size_t)g*512 + 2*t) = sB;
}

// ---------------- KR2: final reduce -> mu, rstd ----------------
__global__ void kR2_stats(const float* __restrict__ qA, const float* __restrict__ qB,
                          float* __restrict__ mu, float* __restrict__ rstd)
{
  int f = blockIdx.x, t = threadIdx.x;   // 512 blocks x 256 threads
  float s = 0.f, q = 0.f;
  #pragma unroll
  for (int k = 0; k < 2; ++k) {
    int g = t + k*256;
    s += qA[(size_t)g*512 + f];
    q += qB[(size_t)g*512 + f];
  }
  #pragma unroll
  for (int off = 1; off < 64; off <<= 1) {
    s += __shfl_xor(s, off);
    q += __shfl_xor(q, off);
  }
  __shared__ float ls[4], lq[4];
  if ((t & 63) == 0) { ls[t >> 6] = s; lq[t >> 6] = q; }
  __syncthreads();
  if (t == 0) {
    float S = ls[0]+ls[1]+ls[2]+ls[3];
    float Q = lq[0]+lq[1]+lq[2]+lq[3];
    float m = S * (1.f/262144.f);
    float v = Q * (1.f/262144.f) - m*m;   // biased variance
    mu[f] = m;
    rstd[f] = 1.f / sqrtf(v + 1e-5f);
  }
}

// ---------------- K2b: fold BN into W1 ----------------
__global__ void k2b_fold(const float* __restrict__ W1, const float* __restrict__ b1,
                         const float* __restrict__ mu, const float* __restrict__ rstd,
                         u16* __restrict__ W1s, float* __restrict__ b1eff)
{
  int o = blockIdx.x, t = threadIdx.x;   // 256 blocks x 256 threads
  float local = 0.f;
  #pragma unroll
  for (int k = 0; k < 2; ++k) {
    int f = t + k*256;
    float w = W1[o*512 + f];
    float r = rstd[f];
    W1s[o*512 + f] = f2bf(w * r);
    local += w * r * mu[f];
  }
  #pragma unroll
  for (int off = 1; off < 64; off <<= 1) local += __shfl_xor(local, off);
  __shared__ float ls[4];
  if ((t & 63) == 0) ls[t >> 6] = local;
  __syncthreads();
  if (t == 0) b1eff[o] = b1[o] - (ls[0]+ls[1]+ls[2]+ls[3]);
}

// ---------------- K3: attention recompute + MLP head ----------------
__global__ __launch_bounds__(512) __attribute__((amdgpu_waves_per_eu(1, 2)))
void k3_mlp(
    const float* __restrict__ x,
    const u16* __restrict__ wEmb, const float* __restrict__ be,
    const float* __restrict__ bk1, const float* __restrict__ bk2,
    const u16* __restrict__ wV, const float* __restrict__ bv,
    const float* __restrict__ wrow,
    const u16* __restrict__ W1s, const float* __restrict__ b1eff,
    const u16* __restrict__ wW2, const float* __restrict__ b2,
    const float* __restrict__ W3, const float* __restrict__ b3,
    float* __restrict__ out)
{
  __shared__ __align__(16) u8 smem[SMEM_BYTES];
  const int t = threadIdx.x;
  const int wt = blockIdx.x;
  const int rowbase = wt * 64;
  const int lane = t & 63;
  const int lr = lane & 15, hi = lane >> 4;
  s16x8 ld[4];

  // chunks 7,8 = W1s kh0 c0,c1
  int p = attn_iters(smem, x, rowbase, wEmb, be, bk1, bk2, wV, bv, wrow,
                     W1s, 512, W1s + 32768, 512, t, lr, hi, ld);

  const int wv_ = t >> 6;
  const int scg = wv_ & 1, mg1 = wv_ >> 1;     // 2 super-col groups x 4 row groups
  const int colA = scg*32 + lr, colB = scg*32 + 16 + lr;

  // B-frags: e_q for both owned col groups (ratio-2 A reuse)
  s16x8 beq0[8], beq1[8];
  #pragma unroll
  for (int ks = 0; ks < 8; ++ks) {
    beq0[ks] = *(const s16x8*)(smem + ACT_EQ + colA*528 + ks*64 + hi*16);
    beq1[ks] = *(const s16x8*)(smem + ACT_EQ + colB*528 + ks*64 + hi*16);
  }

  f32x4 acc[4][2];
  #pragma unroll
  for (int c = 0; c < 4; ++c) { acc[c][0] = {0.f,0.f,0.f,0.f}; acc[c][1] = {0.f,0.f,0.f,0.f}; }

  // i7..i10: GEMM1 kh0 (K = e_q)
  #pragma unroll
  for (int c = 0; c < 4; ++c) {
    ldw_write(smem + WBo(p^1), t, ld);
    const u16* nx = (c == 0) ? W1s + 2*32768 : (c == 1) ? W1s + 3*32768
                  : (c == 2) ? W1s + 256      : W1s + 256 + 32768;
    ldw_issue(nx, 512, t, ld);
    #pragma unroll
    for (int ks = 0; ks < 8; ++ks) {
      s16x8 a = *(const s16x8*)(smem + WBo(p) + (mg1*16 + lr)*528 + ks*64 + hi*16);
      acc[c][0] = MFMA(a, beq0[ks], acc[c][0], 0, 0, 0);
      acc[c][1] = MFMA(a, beq1[ks], acc[c][1], 0, 0, 0);
    }
    BARX(); p ^= 1;
  }

  // B-frags: atten
  s16x8 bat0[8], bat1[8];
  #pragma unroll
  for (int ks = 0; ks < 8; ++ks) {
    bat0[ks] = *(const s16x8*)(smem + ACT_WK + colA*528 + ks*64 + hi*16);
    bat1[ks] = *(const s16x8*)(smem + ACT_WK + colB*528 + ks*64 + hi*16);
  }

  // i11..i14: GEMM1 kh1 (K = atten); h1 -> ACT_EQ at the end
  #pragma unroll
  for (int c = 0; c < 4; ++c) {
    ldw_write(smem + WBo(p^1), t, ld);
    if (c == 0)      ldw_issue(W1s + 256 + 2*32768, 512, t, ld);
    else if (c == 1) ldw_issue(W1s + 256 + 3*32768, 512, t, ld);
    else if (c == 2) ldw_issue(wW2, 256, t, ld);
    else             ldw_issue(wW2 + 16384, 256, t, ld);
    #pragma unroll
    for (int ks = 0; ks < 8; ++ks) {
      s16x8 a = *(const s16x8*)(smem + WBo(p) + (mg1*16 + lr)*528 + ks*64 + hi*16);
      acc[c][0] = MFMA(a, bat0[ks], acc[c][0], 0, 0, 0);
      acc[c][1] = MFMA(a, bat1[ks], acc[c][1], 0, 0, 0);
    }
    if (c == 3) {
      #pragma unroll
      for (int cc = 0; cc < 4; ++cc) {
        f32x4 bb = ((const f32x4*)b1eff)[cc*16 + mg1*4 + hi];
        #pragma unroll
        for (int cg = 0; cg < 2; ++cg) {
          int col = scg*32 + cg*16 + lr;
          s16x4 pk;
          #pragma unroll
          for (int r = 0; r < 4; ++r) {
            float v = acc[cc][cg][r] + bb[r];
            pk[r] = (short)f2bf((v > 0.f) ? v : 0.f);
          }
          *(s16x4*)(smem + ACT_EQ + col*528 + cc*128 + mg1*32 + hi*8) = pk;
        }
      }
    }
    BARX(); p ^= 1;
  }

  // B-frags: h1
  s16x8 bh0[8], bh1[8];
  #pragma unroll
  for (int ks = 0; ks < 8; ++ks) {
    bh0[ks] = *(const s16x8*)(smem + ACT_EQ + colA*528 + ks*64 + hi*16);
    bh1[ks] = *(const s16x8*)(smem + ACT_EQ + colB*528 + ks*64 + hi*16);
  }

  f32x4 acc2[2][2];
  #pragma unroll
  for (int c = 0; c < 2; ++c) { acc2[c][0] = {0.f,0.f,0.f,0.f}; acc2[c][1] = {0.f,0.f,0.f,0.f}; }

  // i15: W2 chunk 0
  ldw_write(smem + WBo(p^1), t, ld);
  #pragma unroll
  for (int ks = 0; ks < 8; ++ks) {
    s16x8 a = *(const s16x8*)(smem + WBo(p) + (mg1*16 + lr)*528 + ks*64 + hi*16);
    acc2[0][0] = MFMA(a, bh0[ks], acc2[0][0], 0, 0, 0);
    acc2[0][1] = MFMA(a, bh1[ks], acc2[0][1], 0, 0, 0);
  }
  BARX(); p ^= 1;

  // i16: W2 chunk 1 ; h2 -> ACT_WK
  #pragma unroll
  for (int ks = 0; ks < 8; ++ks) {
    s16x8 a = *(const s16x8*)(smem + WBo(p) + (mg1*16 + lr)*528 + ks*64 + hi*16);
    acc2[1][0] = MFMA(a, bh0[ks], acc2[1][0], 0, 0, 0);
    acc2[1][1] = MFMA(a, bh1[ks], acc2[1][1], 0, 0, 0);
  }
  #pragma unroll
  for (int c = 0; c < 2; ++c) {
    f32x4 bb = ((const f32x4*)b2)[c*16 + mg1*4 + hi];
    #pragma unroll
    for (int cg = 0; cg < 2; ++cg) {
      int col = scg*32 + cg*16 + lr;
      s16x4 pk;
      #pragma unroll
      for (int r = 0; r < 4; ++r) {
        float v = acc2[c][cg][r] + bb[r];
        pk[r] = (short)f2bf((v > 0.f) ? v : 0.f);
      }
      *(s16x4*)(smem + ACT_WK + col*528 + c*128 + mg1*32 + hi*8) = pk;
    }
  }
  BARX();

  // out = W3 . h2 + b3 (one thread per row)
  if (t < 64) {
    float s = b3[0];
    #pragma unroll
    for (int jj = 0; jj < 16; ++jj) {
      const u32x4 v = *(const u32x4*)(smem + ACT_WK + t*528 + jj*16);
      #pragma unroll
      for (int q2 = 0; q2 < 4; ++q2) {
        u32 u = v[q2];
        s += bf2f((u16)(u & 0xFFFFu)) * W3[jj*8 + q2*2];
        s += bf2f((u16)(u >> 16))     * W3[jj*8 + q2*2 + 1];
      }
    }
    out[rowbase + t] = s;
  }
}

extern "C" void kernel_launch(void* const* d_in, const int* in_sizes, int n_in,
                              void* d_out, int out_size, void* d_ws, size_t ws_size,
                              hipStream_t stream)
{
  const float* x   = (const float*)d_in[0];
  const float* We  = (const float*)d_in[1];
  const float* be  = (const float*)d_in[2];
  const float* Wk1 = (const float*)d_in[3];
  const float* bk1 = (const float*)d_in[4];
  const float* Wk2 = (const float*)d_in[5];
  const float* bk2 = (const float*)d_in[6];
  const float* Wq  = (const float*)d_in[7];
  const float* Wk  = (const float*)d_in[8];
  const float* Wv  = (const float*)d_in[9];
  const float* bv  = (const float*)d_in[10];
  const float* W1  = (const float*)d_in[11];
  const float* b1  = (const float*)d_in[12];
  const float* W2  = (const float*)d_in[13];
  const float* b2  = (const float*)d_in[14];
  const float* W3  = (const float*)d_in[15];
  const float* b3  = (const float*)d_in[16];

  u8* ws = (u8*)d_ws;
  float* pA    = (float*)(ws + PA_OFF);
  float* pB    = (float*)(ws + PB_OFF);
  float* qA    = (float*)(ws + QA_OFF);
  float* qB    = (float*)(ws + QB_OFF);
  float* mu    = (float*)(ws + MU_OFF);
  float* rstd  = (float*)(ws + RSTD_OFF);
  float* b1eff = (float*)(ws + B1E_OFF);
  u16*   wEmb  = (u16*)(ws + WEMB_OFF);
  u16*   wVb   = (u16*)(ws + WV_OFF);
  u16*   wW2   = (u16*)(ws + W2_OFF);
  u16*   wW1s  = (u16*)(ws + W1S_OFF);
  float* Wu    = (float*)(ws + WU_OFF);
  float* G     = (float*)(ws + G_OFF);
  float* g     = (float*)(ws + GG_OFF);
  float* scp   = (float*)(ws + SCP_OFF);
  float* wrow  = (float*)(ws + WROW_OFF);

  k0_convert<<<dim3(480), dim3(256), 0, stream>>>(We, Wk1, Wk2, Wv, W2, wEmb, wVb, wW2);
  k0b_wu<<<dim3(256), dim3(256), 0, stream>>>(Wq, Wk, Wu);
  k0c_G<<<dim3(2), dim3(256), 0, stream>>>(Wu, Wk1, bk1, Wk2, bk2, G, g);
  k0d_M<<<dim3(2), dim3(256), 0, stream>>>(We, be, G, g, scp);
  k0e_scores<<<dim3(1024), dim3(256), 0, stream>>>(x, scp, wrow);
  k1_attn<<<dim3(NTILE), dim3(512), 0, stream>>>(x, wEmb, be, bk1, bk2, wVb, bv, wrow, pA, pB);
  kR1_reduce<<<dim3(512), dim3(256), 0, stream>>>(pA, pB, qA, qB);
  kR2_stats<<<dim3(512), dim3(256), 0, stream>>>(qA, qB, mu, rstd);
  k2b_fold<<<dim3(256), dim3(256), 0, stream>>>(W1, b1, mu, rstd, wW1s, b1eff);
  k3_mlp<<<dim3(NTILE), dim3(512), 0, stream>>>(x, wEmb, be, bk1, bk2, wVb, bv, wrow,
                                                wW1s, b1eff, wW2, b2, W3, b3,
                                                (float*)d_out);
}

// Round 9
// 520.401 us; speedup vs baseline: 1.3940x; 1.0457x over previous
//
#include <hip/hip_runtime.h>
#include <cstdint>
#include <cstddef>

typedef unsigned char  u8;
typedef unsigned short u16;
typedef unsigned int   u32;

typedef __attribute__((ext_vector_type(8))) short s16x8;
typedef __attribute__((ext_vector_type(4))) short s16x4;
typedef __attribute__((ext_vector_type(4))) float f32x4;
typedef __attribute__((ext_vector_type(4))) u32   u32x4;

#define NTILE 2048   // 262144 / 128 rows per tile

// LDS: ACT_EQ 64KB + ACT_WK 64KB + WB 2x16KB = 160KB
#define ACT_EQ 0
#define ACT_WK 65536
#define WB0_OFF 131072
#define WBSZ    16384
#define SMEM_BYTES 163840
#define WBo(p) (WB0_OFF + (p)*WBSZ)

// XOR-swizzled layouts (bank-uniform for b128 reads/writes and b64 stores)
#define AIDX(col, fb) ((((col)*512) + (fb)) ^ (((col)&7) << 4))   // act [128 col][512B]
#define WIDX(row, kb) ((((row)*256) + (kb)) ^ (((row)&7) << 4))   // wchunk [64 row][256B]
#define EIDX(row, kb) ((((row)*64)  + (kb)) ^ (((row)&3) << 4))   // emb [256 row][64B]

#define MFMA __builtin_amdgcn_mfma_f32_16x16x32_bf16

// raw barrier: LDS visibility without draining vmem (prefetch survives)
#define BARX() do { __builtin_amdgcn_sched_barrier(0); \
  asm volatile("s_waitcnt lgkmcnt(0)"); \
  __builtin_amdgcn_s_barrier(); \
  __builtin_amdgcn_sched_barrier(0); } while (0)

// ---------------- workspace layout (bytes), total ~11.3 MB ----------------
static const size_t PA_OFF   = 0;          // f32 [2048 tile][512 f]
static const size_t PB_OFF   = 4194304;
static const size_t QA_OFF   = 8388608;    // f32 [256 g][512 f]
static const size_t QB_OFF   = 8912896;
static const size_t MU_OFF   = 9437184;
static const size_t RSTD_OFF = 9439232;
static const size_t B1E_OFF  = 9441280;
static const size_t WEMB_OFF = 9442304;    // bf16 [3][256][32]
static const size_t WV_OFF   = 9491456;    // bf16 [256][256]
static const size_t W2_OFF   = 9622528;    // bf16 [128][256]
static const size_t W1S_OFF  = 9688064;    // bf16 [256][512]
static const size_t WU_OFF   = 9950208;    // f32 [256][256]
static const size_t G_OFF    = 10212352;   // f32 [2][256][13]
static const size_t GG_OFF   = 10238976;   // f32 [2][256]
static const size_t SCP_OFF  = 10241024;   // f32 [2][256]
static const size_t WROW_OFF = 10243072;   // f32 [262144]
// end = 11291648

__device__ __forceinline__ u16 f2bf(float f) {
  u32 u = __builtin_bit_cast(u32, f);
  u += 0x7FFFu + ((u >> 16) & 1u);     // RNE
  return (u16)(u >> 16);
}
__device__ __forceinline__ float bf2f(u16 h) {
  u32 u = ((u32)h) << 16;
  return __builtin_bit_cast(float, u);
}

// ---------------- K0 setup kernels ----------------
__global__ void k0_convert(const float* __restrict__ We,  const float* __restrict__ Wk1,
                           const float* __restrict__ Wk2, const float* __restrict__ Wv,
                           const float* __restrict__ W2,
                           u16* __restrict__ wEmb, u16* __restrict__ wV, u16* __restrict__ wW2)
{
  int i = blockIdx.x * 256 + threadIdx.x;
  if (i < 24576) {
    int which = i >> 13, rem = i & 8191, h = rem >> 5, c = rem & 31;
    const float* W = (which == 0) ? We : (which == 1) ? Wk1 : Wk2;
    wEmb[i] = (c < 13) ? f2bf(W[h*13 + c]) : (u16)0;
  } else if (i < 24576 + 65536) {
    int j = i - 24576;
    wV[j] = f2bf(Wv[j]);
  } else if (i < 24576 + 65536 + 32768) {
    int j = i - 90112;
    wW2[j] = f2bf(W2[j]);
  }
}

__global__ void k0b_wu(const float* __restrict__ Wq, const float* __restrict__ Wk,
                       float* __restrict__ Wu)
{
  int a = blockIdx.x, b = threadIdx.x;
  float acc = 0.f;
  #pragma unroll 4
  for (int h = 0; h < 256; ++h)
    acc += Wq[h*256 + a] * Wk[h*256 + b];
  Wu[a*256 + b] = acc;
}

__global__ void k0c_G(const float* __restrict__ Wu,
                      const float* __restrict__ Wk1, const float* __restrict__ bk1,
                      const float* __restrict__ Wk2, const float* __restrict__ bk2,
                      float* __restrict__ G, float* __restrict__ g)
{
  int j = blockIdx.x, a = threadIdx.x;
  const float* Wkj = j ? Wk2 : Wk1;
  const float* bkj = j ? bk2 : bk1;
  float acc[13];
  #pragma unroll
  for (int q = 0; q < 13; ++q) acc[q] = 0.f;
  float ga = 0.f;
  for (int b = 0; b < 256; ++b) {
    float wu = Wu[a*256 + b];
    #pragma unroll
    for (int q = 0; q < 13; ++q) acc[q] += wu * Wkj[b*13 + q];
    ga += wu * bkj[b];
  }
  #pragma unroll
  for (int q = 0; q < 13; ++q) G[j*3328 + a*13 + q] = acc[q];
  g[j*256 + a] = ga;
}

__global__ void k0d_M(const float* __restrict__ We, const float* __restrict__ be,
                      const float* __restrict__ G, const float* __restrict__ g,
                      float* __restrict__ scp)
{
  int j = blockIdx.x, t = threadIdx.x;
  float acc = 0.f;
  if (t < 169) {
    int p = t / 13, q = t - p*13;
    for (int a = 0; a < 256; ++a) acc += We[a*13 + p] * G[j*3328 + a*13 + q];
    scp[j*256 + t] = acc;
  } else if (t < 182) {
    int p = t - 169;
    for (int a = 0; a < 256; ++a) acc += We[a*13 + p] * g[j*256 + a];
    scp[j*256 + t] = acc;
  } else if (t < 195) {
    int q = t - 182;
    for (int a = 0; a < 256; ++a) acc += be[a] * G[j*3328 + a*13 + q];
    scp[j*256 + t] = acc;
  } else if (t == 195) {
    for (int a = 0; a < 256; ++a) acc += be[a] * g[j*256 + a];
    scp[j*256 + 195] = acc;
  }
}

__global__ __launch_bounds__(256) void k0e_scores(const float* __restrict__ x,
                                                  const float* __restrict__ scp,
                                                  float* __restrict__ wrow)
{
  int row = blockIdx.x * 256 + threadIdx.x;
  const float* xr = x + (size_t)row*39;
  float f0[13], f1[13], f2[13];
  #pragma unroll
  for (int p = 0; p < 12; ++p) { f0[p] = xr[p]; f1[p] = xr[12+p]; f2[p] = xr[24+p]; }
  f0[12] = xr[36]; f1[12] = xr[37]; f2[12] = xr[38];

  auto score = [&](const float* __restrict__ P, const float (&fj)[13]) -> float {
    float s = P[195];
    #pragma unroll
    for (int p = 0; p < 13; ++p) {
      float tp = P[169 + p];
      #pragma unroll
      for (int q = 0; q < 13; ++q) tp += P[p*13 + q] * fj[q];
      s += f0[p] * tp;
    }
    #pragma unroll
    for (int q = 0; q < 13; ++q) s += P[182 + q] * fj[q];
    return s;
  };
  float s1 = score(scp, f1);
  float s2 = score(scp + 256, f2);
  wrow[row] = 1.f / (1.f + __expf((s2 - s1) * 0.0625f));   // /sqrt(256)
}

// ---------------- staging (512 threads, 16KB chunks, 2 b128 per thread) ----------------
__device__ __forceinline__ void ldw_issue(const u16* __restrict__ src, int stride,
                                          int t, s16x8* ld)
{
  #pragma unroll
  for (int i = 0; i < 2; ++i) {
    int u = t + i*512;
    ld[i] = *(const s16x8*)(src + (u >> 4)*stride + (u & 15)*8);
  }
}
__device__ __forceinline__ void ldw_write(u8* __restrict__ smem_, int p, int t, const s16x8* ld)
{
  #pragma unroll
  for (int i = 0; i < 2; ++i) {
    int u = t + i*512;
    *(s16x8*)(smem_ + WBo(p) + WIDX(u >> 4, (u & 15)*16)) = ld[i];
  }
}
__device__ __forceinline__ void lde_issue(const u16* __restrict__ src, int t, s16x8* ld)
{
  #pragma unroll
  for (int i = 0; i < 2; ++i) {
    int u = t + i*512;
    ld[i] = *(const s16x8*)(src + (u >> 2)*32 + (u & 3)*8);
  }
}
__device__ __forceinline__ void lde_write(u8* __restrict__ smem_, int p, int t, const s16x8* ld)
{
  #pragma unroll
  for (int i = 0; i < 2; ++i) {
    int u = t + i*512;
    *(s16x8*)(smem_ + WBo(p) + EIDX(u >> 2, (u & 3)*16)) = ld[i];
  }
}

__device__ __forceinline__ s16x8 make_bfr(const float* __restrict__ xr, int a, int hi)
{
  s16x8 v = {0,0,0,0,0,0,0,0};
  if (hi == 0) {
    #pragma unroll
    for (int e = 0; e < 8; ++e) v[e] = (short)f2bf(xr[12*a + e]);
  } else if (hi == 1) {
    #pragma unroll
    for (int e = 0; e < 4; ++e) v[e] = (short)f2bf(xr[12*a + 8 + e]);
    v[4] = (short)f2bf(xr[36 + a]);
  }
  return v;
}

// embed: wave covers its own 16 cols (clE), all 256 feats
__device__ __forceinline__ void embed_compute(const u8* __restrict__ wb, u8* __restrict__ act,
    const float* __restrict__ bias, s16x8 b, int clE, int lr, int hi)
{
  #pragma unroll
  for (int m = 0; m < 16; ++m) {
    s16x8 a = *(const s16x8*)(wb + EIDX(m*16 + lr, hi*16));
    f32x4 k4 = {0.f,0.f,0.f,0.f};
    k4 = MFMA(a, b, k4, 0, 0, 0);
    f32x4 bb = ((const f32x4*)bias)[m*4 + hi];
    s16x4 pk;
    #pragma unroll
    for (int r = 0; r < 4; ++r) pk[r] = (short)f2bf(k4[r] + bb[r]);
    *(s16x4*)(act + AIDX(clE, m*32 + hi*8)) = pk;
  }
}

// ---- pipelined attention: e_q -> ACT_EQ, atten -> ACT_WK; returns WB parity ----
__device__ __forceinline__ int attn_run(
    u8* __restrict__ smem, const float* __restrict__ x, int rowbase,
    const u16* __restrict__ wEmb, const float* __restrict__ be,
    const float* __restrict__ bk1, const float* __restrict__ bk2,
    const u16* __restrict__ wV, const float* __restrict__ bv,
    const float* __restrict__ wrow,
    const u16* __restrict__ n19, int s19, const u16* __restrict__ n20, int s20,
    int t, int lr, int hi, s16x8* ld)
{
  const int wv_ = t >> 6;
  const int colgV = wv_ & 3, mgV = wv_ >> 2;     // V split: 4 colg x 2 mg
  const int clE = wv_*16 + lr;                   // embed col
  const float* xr = x + (size_t)(rowbase + clE)*39;
  s16x8 bfr0 = make_bfr(xr, 0, hi);
  s16x8 bfr1 = make_bfr(xr, 1, hi);
  s16x8 bfr2 = make_bfr(xr, 2, hi);
  float w1c[2];
  #pragma unroll
  for (int cg = 0; cg < 2; ++cg) w1c[cg] = wrow[rowbase + colgV*32 + cg*16 + lr];

  // prologue: emb0 -> WB0; emb1 in ld
  lde_issue(wEmb, t, ld);
  lde_write(smem, 0, t, ld);
  lde_issue(wEmb + 8192, t, ld);
  BARX();
  int p = 0;

  // c0: emb0 -> e_q
  lde_write(smem, p^1, t, ld);
  ldw_issue(wV, 256, t, ld);                        // c2 = V(q0,o0)
  embed_compute(smem + WBo(p), smem + ACT_EQ, be, bfr0, clE, lr, hi);
  BARX(); p ^= 1;

  // c1: emb1 -> e_k1
  ldw_write(smem, p^1, t, ld);
  ldw_issue(wV + 16384, 256, t, ld);                // c3 = V(q0,o1)
  embed_compute(smem + WBo(p), smem + ACT_WK, bk1, bfr1, clE, lr, hi);
  BARX(); p ^= 1;

  f32x4 accV1[4][2][2];
  #pragma unroll
  for (int o = 0; o < 4; ++o)
    #pragma unroll
    for (int m = 0; m < 2; ++m)
      #pragma unroll
      for (int cg = 0; cg < 2; ++cg) accV1[o][m][cg] = {0.f,0.f,0.f,0.f};
  s16x8 bqv[2][4];

  // pass1: chunks c2..c9 = V(q=idx>>2, o=idx&3), B = e_k1
  #pragma unroll
  for (int idx = 0; idx < 8; ++idx) {
    const int q = idx >> 2, o = idx & 3;
    if ((idx & 3) == 0) {
      #pragma unroll
      for (int cg = 0; cg < 2; ++cg)
        #pragma unroll
        for (int ksl = 0; ksl < 4; ++ksl)
          bqv[cg][ksl] = *(const s16x8*)(smem + ACT_WK +
              AIDX(colgV*32 + cg*16 + lr, q*256 + ksl*64 + hi*16));
    }
    if (idx < 7) ldw_write(smem, p^1, t, ld);
    else         lde_write(smem, p^1, t, ld);       // c10 = emb2
    if (idx < 6)      { const int j = idx + 2; ldw_issue(wV + (j&3)*16384 + (j>>2)*128, 256, t, ld); }
    else if (idx == 6) lde_issue(wEmb + 16384, t, ld);          // c10
    else               ldw_issue(wV, 256, t, ld);               // c11 = V(q0,o0) pass2
    #pragma unroll
    for (int ksl = 0; ksl < 4; ++ksl) {
      s16x8 a0 = *(const s16x8*)(smem + WBo(p) + WIDX(mgV*32 + lr,      ksl*64 + hi*16));
      s16x8 a1 = *(const s16x8*)(smem + WBo(p) + WIDX(mgV*32 + 16 + lr, ksl*64 + hi*16));
      #pragma unroll
      for (int cg = 0; cg < 2; ++cg) {
        accV1[o][0][cg] = MFMA(a0, bqv[cg][ksl], accV1[o][0][cg], 0, 0, 0);
        accV1[o][1][cg] = MFMA(a1, bqv[cg][ksl], accV1[o][1][cg], 0, 0, 0);
      }
    }
    BARX(); p ^= 1;
  }

  // c10: emb2 -> e_k2 (WK overwrite; e_k1 reads all done)
  ldw_write(smem, p^1, t, ld);                      // c11
  ldw_issue(wV + 16384, 256, t, ld);                // c12 = V(q0,o1)
  embed_compute(smem + WBo(p), smem + ACT_WK, bk2, bfr2, clE, lr, hi);
  BARX(); p ^= 1;

  f32x4 accV2[4][2][2];
  #pragma unroll
  for (int o = 0; o < 4; ++o)
    #pragma unroll
    for (int m = 0; m < 2; ++m)
      #pragma unroll
      for (int cg = 0; cg < 2; ++cg) accV2[o][m][cg] = {0.f,0.f,0.f,0.f};

  // pass2: chunks c11..c18, B = e_k2; combine+atten at end
  #pragma unroll
  for (int idx = 0; idx < 8; ++idx) {
    const int q = idx >> 2, o = idx & 3;
    if ((idx & 3) == 0) {
      #pragma unroll
      for (int cg = 0; cg < 2; ++cg)
        #pragma unroll
        for (int ksl = 0; ksl < 4; ++ksl)
          bqv[cg][ksl] = *(const s16x8*)(smem + ACT_WK +
              AIDX(colgV*32 + cg*16 + lr, q*256 + ksl*64 + hi*16));
    }
    if (idx < 7)       ldw_write(smem, p^1, t, ld);
    else if (n19)      ldw_write(smem, p^1, t, ld);  // c19
    if (idx < 6)       { const int j = idx + 2; ldw_issue(wV + (j&3)*16384 + (j>>2)*128, 256, t, ld); }
    else if (idx == 6) { if (n19) ldw_issue(n19, s19, t, ld); }
    else               { if (n20) ldw_issue(n20, s20, t, ld); }
    #pragma unroll
    for (int ksl = 0; ksl < 4; ++ksl) {
      s16x8 a0 = *(const s16x8*)(smem + WBo(p) + WIDX(mgV*32 + lr,      ksl*64 + hi*16));
      s16x8 a1 = *(const s16x8*)(smem + WBo(p) + WIDX(mgV*32 + 16 + lr, ksl*64 + hi*16));
      #pragma unroll
      for (int cg = 0; cg < 2; ++cg) {
        accV2[o][0][cg] = MFMA(a0, bqv[cg][ksl], accV2[o][0][cg], 0, 0, 0);
        accV2[o][1][cg] = MFMA(a1, bqv[cg][ksl], accV2[o][1][cg], 0, 0, 0);
      }
    }
    if (idx == 7) {
      // softmax combine -> atten -> WK (all pass2 B-hoists done at idx 4)
      #pragma unroll
      for (int oo = 0; oo < 4; ++oo)
        #pragma unroll
        for (int m = 0; m < 2; ++m) {
          f32x4 bb = ((const f32x4*)bv)[oo*16 + mgV*8 + m*4 + hi];
          #pragma unroll
          for (int cg = 0; cg < 2; ++cg) {
            s16x4 pk;
            #pragma unroll
            for (int r = 0; r < 4; ++r) {
              float va = accV1[oo][m][cg][r] + bb[r]; va = (va > 0.f) ? va : 0.01f*va;
              float vb = accV2[oo][m][cg][r] + bb[r]; vb = (vb > 0.f) ? vb : 0.01f*vb;
              pk[r] = (short)f2bf(w1c[cg]*va + (1.f - w1c[cg])*vb);
            }
            *(s16x4*)(smem + ACT_WK +
                AIDX(colgV*32 + cg*16 + lr, oo*128 + mgV*64 + m*32 + hi*8)) = pk;
          }
        }
    }
    BARX(); p ^= 1;
  }
  return p;
}

// ---------------- K1: attention -> BN partial sums ----------------
__global__ __launch_bounds__(512) __attribute__((amdgpu_waves_per_eu(1, 2)))
void k1_attn(
    const float* __restrict__ x,
    const u16* __restrict__ wEmb, const float* __restrict__ be,
    const float* __restrict__ bk1, const float* __restrict__ bk2,
    const u16* __restrict__ wV, const float* __restrict__ bv,
    const float* __restrict__ wrow,
    float* __restrict__ pA, float* __restrict__ pB)
{
  __shared__ __align__(16) u8 smem[SMEM_BYTES];
  const int t = threadIdx.x;
  const int wt = blockIdx.x;
  const int rowbase = wt * 128;
  const int lane = t & 63;
  const int lr = lane & 15, hi = lane >> 4;
  s16x8 ld[2];

  attn_run(smem, x, rowbase, wEmb, be, bk1, bk2, wV, bv, wrow,
           nullptr, 0, nullptr, 0, t, lr, hi, ld);

  // stats: thread t = (fg = t&63 feat-octet, cb = t>>6 col-block of 16)
  const int fg = t & 63, cb = t >> 6;
  const u8* rg = smem + ((fg & 32) ? ACT_WK : ACT_EQ);
  const int fb = (fg & 31) * 16;
  float s[8], q[8];
  #pragma unroll
  for (int e = 0; e < 8; ++e) { s[e] = 0.f; q[e] = 0.f; }
  #pragma unroll 4
  for (int c = 0; c < 16; ++c) {
    int col = cb*16 + c;
    u32x4 v = *(const u32x4*)(rg + AIDX(col, fb));
    #pragma unroll
    for (int j = 0; j < 4; ++j) {
      float a = bf2f((u16)(v[j] & 0xFFFFu));
      float b = bf2f((u16)(v[j] >> 16));
      s[2*j] += a; q[2*j] += a*a;
      s[2*j+1] += b; q[2*j+1] += b*b;
    }
  }
  // cb-reduction via WB scratch: sb[8*f + cb], qb at +4096 floats
  float* sb = (float*)(smem + WB0_OFF);
  #pragma unroll
  for (int e = 0; e < 8; ++e) {
    sb[(fg*8 + e)*8 + cb]        = s[e];
    sb[4096 + (fg*8 + e)*8 + cb] = q[e];
  }
  __syncthreads();
  {
    int f = t;   // 512 feats
    float ss = 0.f, qs = 0.f;
    #pragma unroll
    for (int c2 = 0; c2 < 8; ++c2) { ss += sb[f*8 + c2]; qs += sb[4096 + f*8 + c2]; }
    pA[(size_t)wt*512 + f] = ss;
    pB[(size_t)wt*512 + f] = qs;
  }
}

// ---------------- KR1: 2048 tiles -> 256 groups ----------------
__global__ void kR1_reduce(const float* __restrict__ pA, const float* __restrict__ pB,
                           float* __restrict__ qA, float* __restrict__ qB)
{
  int g = blockIdx.x, t = threadIdx.x;   // 256 x 256
  float2 sA = make_float2(0.f, 0.f), sB = make_float2(0.f, 0.f);
  #pragma unroll
  for (int k = 0; k < 8; ++k) {
    size_t wg = (size_t)g*8 + k;
    float2 a = *(const float2*)(pA + wg*512 + 2*t);
    float2 b = *(const float2*)(pB + wg*512 + 2*t);
    sA.x += a.x; sA.y += a.y; sB.x += b.x; sB.y += b.y;
  }
  *(float2*)(qA + (size_t)g*512 + 2*t) = sA;
  *(float2*)(qB + (size_t)g*512 + 2*t) = sB;
}

// ---------------- KR2: final reduce -> mu, rstd ----------------
__global__ void kR2_stats(const float* __restrict__ qA, const float* __restrict__ qB,
                          float* __restrict__ mu, float* __restrict__ rstd)
{
  int f = blockIdx.x, t = threadIdx.x;   // 512 blocks x 256 threads
  float s = qA[(size_t)t*512 + f];
  float q = qB[(size_t)t*512 + f];
  #pragma unroll
  for (int off = 1; off < 64; off <<= 1) {
    s += __shfl_xor(s, off);
    q += __shfl_xor(q, off);
  }
  __shared__ float ls[4], lq[4];
  if ((t & 63) == 0) { ls[t >> 6] = s; lq[t >> 6] = q; }
  __syncthreads();
  if (t == 0) {
    float S = ls[0]+ls[1]+ls[2]+ls[3];
    float Q = lq[0]+lq[1]+lq[2]+lq[3];
    float m = S * (1.f/262144.f);
    float v = Q * (1.f/262144.f) - m*m;
    mu[f] = m;
    rstd[f] = 1.f / sqrtf(v + 1e-5f);
  }
}

// ---------------- K2b: fold BN into W1 ----------------
__global__ void k2b_fold(const float* __restrict__ W1, const float* __restrict__ b1,
                         const float* __restrict__ mu, const float* __restrict__ rstd,
                         u16* __restrict__ W1s, float* __restrict__ b1eff)
{
  int o = blockIdx.x, t = threadIdx.x;
  float local = 0.f;
  #pragma unroll
  for (int k = 0; k < 2; ++k) {
    int f = t + k*256;
    float w = W1[o*512 + f];
    float r = rstd[f];
    W1s[o*512 + f] = f2bf(w * r);
    local += w * r * mu[f];
  }
  #pragma unroll
  for (int off = 1; off < 64; off <<= 1) local += __shfl_xor(local, off);
  __shared__ float ls[4];
  if ((t & 63) == 0) ls[t >> 6] = local;
  __syncthreads();
  if (t == 0) b1eff[o] = b1[o] - (ls[0]+ls[1]+ls[2]+ls[3]);
}

// ---------------- K3: attention recompute + MLP ----------------
__global__ __launch_bounds__(512) __attribute__((amdgpu_waves_per_eu(1, 2)))
void k3_mlp(
    const float* __restrict__ x,
    const u16* __restrict__ wEmb, const float* __restrict__ be,
    const float* __restrict__ bk1, const float* __restrict__ bk2,
    const u16* __restrict__ wV, const float* __restrict__ bv,
    const float* __restrict__ wrow,
    const u16* __restrict__ W1s, const float* __restrict__ b1eff,
    const u16* __restrict__ wW2, const float* __restrict__ b2,
    const float* __restrict__ W3, const float* __restrict__ b3,
    float* __restrict__ out)
{
  __shared__ __align__(16) u8 smem[SMEM_BYTES];
  const int t = threadIdx.x;
  const int wt = blockIdx.x;
  const int rowbase = wt * 128;
  const int lane = t & 63;
  const int lr = lane & 15, hi = lane >> 4;
  s16x8 ld[2];

  int p = attn_run(smem, x, rowbase, wEmb, be, bk1, bk2, wV, bv, wrow,
                   W1s, 512, W1s + 32768, 512, t, lr, hi, ld);

  const int wv_ = t >> 6;
  const int colg1 = wv_ & 1, mg1 = wv_ >> 1;   // MLP split: 2 colg x 4 mg

  // GEMM1: chunks c19..c34 = W1s(q=idx>>2, o=idx&3); B: q0,q1=e_q, q2,q3=atten
  f32x4 acc1[4][4];
  #pragma unroll
  for (int o = 0; o < 4; ++o)
    #pragma unroll
    for (int cg = 0; cg < 4; ++cg) acc1[o][cg] = {0.f,0.f,0.f,0.f};
  s16x8 bq1[4][4];

  #pragma unroll
  for (int idx = 0; idx < 16; ++idx) {
    const int q = idx >> 2, o = idx & 3;
    if ((idx & 3) == 0) {
      const int areg = (q < 2) ? ACT_EQ : ACT_WK;
      const int qb = (q & 1) * 256;
      #pragma unroll
      for (int cg = 0; cg < 4; ++cg)
        #pragma unroll
        for (int ksl = 0; ksl < 4; ++ksl)
          bq1[cg][ksl] = *(const s16x8*)(smem + areg +
              AIDX(colg1*64 + cg*16 + lr, qb + ksl*64 + hi*16));
    }
    ldw_write(smem, p^1, t, ld);
    if (idx < 14) { const int j = idx + 2; ldw_issue(W1s + (size_t)(j&3)*32768 + (j>>2)*128, 512, t, ld); }
    else          { const int j = idx - 14; ldw_issue(wW2 + (size_t)(j&1)*16384 + (j>>1)*128, 256, t, ld); }
    #pragma unroll
    for (int ksl = 0; ksl < 4; ++ksl) {
      s16x8 a = *(const s16x8*)(smem + WBo(p) + WIDX(mg1*16 + lr, ksl*64 + hi*16));
      #pragma unroll
      for (int cg = 0; cg < 4; ++cg)
        acc1[o][cg] = MFMA(a, bq1[cg][ksl], acc1[o][cg], 0, 0, 0);
    }
    if (idx == 15) {
      // h1 = relu(acc1 + b1eff) -> ACT_EQ (e_q reads done at q1 hoist)
      #pragma unroll
      for (int oo = 0; oo < 4; ++oo) {
        f32x4 bb = ((const f32x4*)b1eff)[oo*16 + mg1*4 + hi];
        #pragma unroll
        for (int cg = 0; cg < 4; ++cg) {
          s16x4 pk;
          #pragma unroll
          for (int r = 0; r < 4; ++r) {
            float v = acc1[oo][cg][r] + bb[r];
            pk[r] = (short)f2bf((v > 0.f) ? v : 0.f);
          }
          *(s16x4*)(smem + ACT_EQ +
              AIDX(colg1*64 + cg*16 + lr, oo*128 + mg1*32 + hi*8)) = pk;
        }
      }
    }
    BARX(); p ^= 1;
  }

  // GEMM2: chunks c35..c38 = W2(q=idx>>1, o=idx&1); B = h1 (EQ)
  f32x4 acc2[2][4];
  #pragma unroll
  for (int o = 0; o < 2; ++o)
    #pragma unroll
    for (int cg = 0; cg < 4; ++cg) acc2[o][cg] = {0.f,0.f,0.f,0.f};

  #pragma unroll
  for (int idx = 0; idx < 4; ++idx) {
    const int q = idx >> 1, o = idx & 1;
    if ((idx & 1) == 0) {
      #pragma unroll
      for (int cg = 0; cg < 4; ++cg)
        #pragma unroll
        for (int ksl = 0; ksl < 4; ++ksl)
          bq1[cg][ksl] = *(const s16x8*)(smem + ACT_EQ +
              AIDX(colg1*64 + cg*16 + lr, q*256 + ksl*64 + hi*16));
    }
    if (idx < 3) ldw_write(smem, p^1, t, ld);
    if (idx < 2) { const int j = idx + 2; ldw_issue(wW2 + (size_t)(j&1)*16384 + (j>>1)*128, 256, t, ld); }
    #pragma unroll
    for (int ksl = 0; ksl < 4; ++ksl) {
      s16x8 a = *(const s16x8*)(smem + WBo(p) + WIDX(mg1*16 + lr, ksl*64 + hi*16));
      #pragma unroll
      for (int cg = 0; cg < 4; ++cg)
        acc2[o][cg] = MFMA(a, bq1[cg][ksl], acc2[o][cg], 0, 0, 0);
    }
    if (idx == 3) {
      // h2 = relu(acc2 + b2) -> ACT_WK (atten reads done at q3 hoist)
      #pragma unroll
      for (int oo = 0; oo < 2; ++oo) {
        f32x4 bb = ((const f32x4*)b2)[oo*16 + mg1*4 + hi];
        #pragma unroll
        for (int cg = 0; cg < 4; ++cg) {
          s16x4 pk;
          #pragma unroll
          for (int r = 0; r < 4; ++r) {
            float v = acc2[oo][cg][r] + bb[r];
            pk[r] = (short)f2bf((v > 0.f) ? v : 0.f);
          }
          *(s16x4*)(smem + ACT_WK +
              AIDX(colg1*64 + cg*16 + lr, oo*128 + mg1*32 + hi*8)) = pk;
        }
      }
    }
    BARX(); p ^= 1;
  }

  // out = W3 . h2 + b3 (one thread per row)
  if (t < 128) {
    float s = b3[0];
    #pragma unroll
    for (int jj = 0; jj < 16; ++jj) {
      const u32x4 v = *(const u32x4*)(smem + ACT_WK + AIDX(t, jj*16));
      #pragma unroll
      for (int q2 = 0; q2 < 4; ++q2) {
        u32 u = v[q2];
        s += bf2f((u16)(u & 0xFFFFu)) * W3[jj*8 + q2*2];
        s += bf2f((u16)(u >> 16))     * W3[jj*8 + q2*2 + 1];
      }
    }
    out[rowbase + t] = s;
  }
}

extern "C" void kernel_launch(void* const* d_in, const int* in_sizes, int n_in,
                              void* d_out, int out_size, void* d_ws, size_t ws_size,
                              hipStream_t stream)
{
  const float* x   = (const float*)d_in[0];
  const float* We  = (const float*)d_in[1];
  const float* be  = (const float*)d_in[2];
  const float* Wk1 = (const float*)d_in[3];
  const float* bk1 = (const float*)d_in[4];
  const float* Wk2 = (const float*)d_in[5];
  const float* bk2 = (const float*)d_in[6];
  const float* Wq  = (const float*)d_in[7];
  const float* Wk  = (const float*)d_in[8];
  const float* Wv  = (const float*)d_in[9];
  const float* bv  = (const float*)d_in[10];
  const float* W1  = (const float*)d_in[11];
  const float* b1  = (const float*)d_in[12];
  const float* W2  = (const float*)d_in[13];
  const float* b2  = (const float*)d_in[14];
  const float* W3  = (const float*)d_in[15];
  const float* b3  = (const float*)d_in[16];

  u8* ws = (u8*)d_ws;
  float* pA    = (float*)(ws + PA_OFF);
  float* pB    = (float*)(ws + PB_OFF);
  float* qA    = (float*)(ws + QA_OFF);
  float* qB    = (float*)(ws + QB_OFF);
  float* mu    = (float*)(ws + MU_OFF);
  float* rstd  = (float*)(ws + RSTD_OFF);
  float* b1eff = (float*)(ws + B1E_OFF);
  u16*   wEmb  = (u16*)(ws + WEMB_OFF);
  u16*   wVb   = (u16*)(ws + WV_OFF);
  u16*   wW2   = (u16*)(ws + W2_OFF);
  u16*   wW1s  = (u16*)(ws + W1S_OFF);
  float* Wu    = (float*)(ws + WU_OFF);
  float* G     = (float*)(ws + G_OFF);
  float* g     = (float*)(ws + GG_OFF);
  float* scp   = (float*)(ws + SCP_OFF);
  float* wrow  = (float*)(ws + WROW_OFF);

  k0_convert<<<dim3(480), dim3(256), 0, stream>>>(We, Wk1, Wk2, Wv, W2, wEmb, wVb, wW2);
  k0b_wu<<<dim3(256), dim3(256), 0, stream>>>(Wq, Wk, Wu);
  k0c_G<<<dim3(2), dim3(256), 0, stream>>>(Wu, Wk1, bk1, Wk2, bk2, G, g);
  k0d_M<<<dim3(2), dim3(256), 0, stream>>>(We, be, G, g, scp);
  k0e_scores<<<dim3(1024), dim3(256), 0, stream>>>(x, scp, wrow);
  k1_attn<<<dim3(NTILE), dim3(512), 0, stream>>>(x, wEmb, be, bk1, bk2, wVb, bv, wrow, pA, pB);
  kR1_reduce<<<dim3(256), dim3(256), 0, stream>>>(pA, pB, qA, qB);
  kR2_stats<<<dim3(512), dim3(256), 0, stream>>>(qA, qB, mu, rstd);
  k2b_fold<<<dim3(256), dim3(256), 0, stream>>>(W1, b1, mu, rstd, wW1s, b1eff);
  k3_mlp<<<dim3(NTILE), dim3(512), 0, stream>>>(x, wEmb, be, bk1, bk2, wVb, bv, wrow,
                                                wW1s, b1eff, wW2, b2, W3, b3,
                                                (float*)d_out);
}

// Round 10
// 495.135 us; speedup vs baseline: 1.4652x; 1.0510x over previous
//
#include <hip/hip_runtime.h>
#include <cstdint>
#include <cstddef>

typedef unsigned char  u8;
typedef unsigned short u16;
typedef unsigned int   u32;

typedef __attribute__((ext_vector_type(8)))  short s16x8;
typedef __attribute__((ext_vector_type(4)))  short s16x4;
typedef __attribute__((ext_vector_type(4)))  float f32x4;
typedef __attribute__((ext_vector_type(16))) float f32x16;
typedef __attribute__((ext_vector_type(4)))  u32   u32x4;

#define NTILE 2048   // 262144 / 128 rows per tile

// LDS: ACT_EQ 64KB + ACT_WK 64KB + WB 2x16KB = 160KB
#define ACT_EQ 0
#define ACT_WK 65536
#define WB0_OFF 131072
#define WBSZ    16384
#define SMEM_BYTES 163840
#define WBo(p) (WB0_OFF + (p)*WBSZ)

// XOR-swizzled layouts
#define AIDX(col, fb)  ((((col)*512) + (fb)) ^ (((col)&7) << 4))   // act [128 col][512B]
#define WIDX(row, kb)  ((((row)*256) + (kb)) ^ (((row)&7) << 4))   // wchunk [64 row][256B]
#define EIDX2(row, kb) ((((row)*32)  + (kb)) ^ ((((row)>>2)&1) << 4)) // emb16 [256 row][32B]

#define MFMA32 __builtin_amdgcn_mfma_f32_32x32x16_bf16

// raw barrier: LDS visibility without draining vmem (prefetch survives)
#define BARX() do { __builtin_amdgcn_sched_barrier(0); \
  asm volatile("s_waitcnt lgkmcnt(0)"); \
  __builtin_amdgcn_s_barrier(); \
  __builtin_amdgcn_sched_barrier(0); } while (0)

// ---------------- workspace layout (bytes), total ~11.3 MB ----------------
static const size_t PA_OFF   = 0;          // f32 [2048 tile][512 f]
static const size_t PB_OFF   = 4194304;
static const size_t QA_OFF   = 8388608;    // f32 [256 g][512 f]
static const size_t QB_OFF   = 8912896;
static const size_t MU_OFF   = 9437184;
static const size_t RSTD_OFF = 9439232;
static const size_t B1E_OFF  = 9441280;
static const size_t WEMB_OFF = 9442304;    // bf16 [3][256][16]
static const size_t WV_OFF   = 9491456;    // bf16 [256][256]
static const size_t W2_OFF   = 9622528;    // bf16 [128][256]
static const size_t W1S_OFF  = 9688064;    // bf16 [256][512]
static const size_t WU_OFF   = 9950208;    // f32 [256][256]
static const size_t G_OFF    = 10212352;   // f32 [2][256][13]
static const size_t GG_OFF   = 10238976;   // f32 [2][256]
static const size_t SCP_OFF  = 10241024;   // f32 [2][256]
static const size_t WROW_OFF = 10243072;   // f32 [262144]
// end = 11291648

__device__ __forceinline__ u16 f2bf(float f) {
  u32 u = __builtin_bit_cast(u32, f);
  u += 0x7FFFu + ((u >> 16) & 1u);     // RNE
  return (u16)(u >> 16);
}
__device__ __forceinline__ float bf2f(u16 h) {
  u32 u = ((u32)h) << 16;
  return __builtin_bit_cast(float, u);
}
__device__ __forceinline__ f32x16 zero16() {
  f32x16 z;
  #pragma unroll
  for (int i = 0; i < 16; ++i) z[i] = 0.f;
  return z;
}

// ---------------- K0 setup kernels ----------------
__global__ void k0_convert(const float* __restrict__ We,  const float* __restrict__ Wk1,
                           const float* __restrict__ Wk2, const float* __restrict__ Wv,
                           const float* __restrict__ W2,
                           u16* __restrict__ wEmb, u16* __restrict__ wV, u16* __restrict__ wW2)
{
  int i = blockIdx.x * 256 + threadIdx.x;
  if (i < 12288) {                          // emb16 [agent][256][16]
    int which = i >> 12, rem = i & 4095, h = rem >> 4, c = rem & 15;
    const float* W = (which == 0) ? We : (which == 1) ? Wk1 : Wk2;
    wEmb[i] = (c < 13) ? f2bf(W[h*13 + c]) : (u16)0;
  } else if (i < 12288 + 65536) {
    int j = i - 12288;
    wV[j] = f2bf(Wv[j]);
  } else if (i < 12288 + 65536 + 32768) {
    int j = i - 77824;
    wW2[j] = f2bf(W2[j]);
  }
}

__global__ void k0b_wu(const float* __restrict__ Wq, const float* __restrict__ Wk,
                       float* __restrict__ Wu)
{
  int a = blockIdx.x, b = threadIdx.x;
  float acc = 0.f;
  #pragma unroll 4
  for (int h = 0; h < 256; ++h)
    acc += Wq[h*256 + a] * Wk[h*256 + b];
  Wu[a*256 + b] = acc;
}

__global__ void k0c_G(const float* __restrict__ Wu,
                      const float* __restrict__ Wk1, const float* __restrict__ bk1,
                      const float* __restrict__ Wk2, const float* __restrict__ bk2,
                      float* __restrict__ G, float* __restrict__ g)
{
  int j = blockIdx.x, a = threadIdx.x;
  const float* Wkj = j ? Wk2 : Wk1;
  const float* bkj = j ? bk2 : bk1;
  float acc[13];
  #pragma unroll
  for (int q = 0; q < 13; ++q) acc[q] = 0.f;
  float ga = 0.f;
  for (int b = 0; b < 256; ++b) {
    float wu = Wu[a*256 + b];
    #pragma unroll
    for (int q = 0; q < 13; ++q) acc[q] += wu * Wkj[b*13 + q];
    ga += wu * bkj[b];
  }
  #pragma unroll
  for (int q = 0; q < 13; ++q) G[j*3328 + a*13 + q] = acc[q];
  g[j*256 + a] = ga;
}

__global__ void k0d_M(const float* __restrict__ We, const float* __restrict__ be,
                      const float* __restrict__ G, const float* __restrict__ g,
                      float* __restrict__ scp)
{
  int j = blockIdx.x, t = threadIdx.x;
  float acc = 0.f;
  if (t < 169) {
    int p = t / 13, q = t - p*13;
    for (int a = 0; a < 256; ++a) acc += We[a*13 + p] * G[j*3328 + a*13 + q];
    scp[j*256 + t] = acc;
  } else if (t < 182) {
    int p = t - 169;
    for (int a = 0; a < 256; ++a) acc += We[a*13 + p] * g[j*256 + a];
    scp[j*256 + t] = acc;
  } else if (t < 195) {
    int q = t - 182;
    for (int a = 0; a < 256; ++a) acc += be[a] * G[j*3328 + a*13 + q];
    scp[j*256 + t] = acc;
  } else if (t == 195) {
    for (int a = 0; a < 256; ++a) acc += be[a] * g[j*256 + a];
    scp[j*256 + 195] = acc;
  }
}

__global__ __launch_bounds__(256) void k0e_scores(const float* __restrict__ x,
                                                  const float* __restrict__ scp,
                                                  float* __restrict__ wrow)
{
  int row = blockIdx.x * 256 + threadIdx.x;
  const float* xr = x + (size_t)row*39;
  float f0[13], f1[13], f2[13];
  #pragma unroll
  for (int p = 0; p < 12; ++p) { f0[p] = xr[p]; f1[p] = xr[12+p]; f2[p] = xr[24+p]; }
  f0[12] = xr[36]; f1[12] = xr[37]; f2[12] = xr[38];

  auto score = [&](const float* __restrict__ P, const float (&fj)[13]) -> float {
    float s = P[195];
    #pragma unroll
    for (int p = 0; p < 13; ++p) {
      float tp = P[169 + p];
      #pragma unroll
      for (int q = 0; q < 13; ++q) tp += P[p*13 + q] * fj[q];
      s += f0[p] * tp;
    }
    #pragma unroll
    for (int q = 0; q < 13; ++q) s += P[182 + q] * fj[q];
    return s;
  };
  float s1 = score(scp, f1);
  float s2 = score(scp + 256, f2);
  wrow[row] = 1.f / (1.f + __expf((s2 - s1) * 0.0625f));   // /sqrt(256)
}

// ---------------- staging (512 threads) ----------------
__device__ __forceinline__ void ldw_issue(const u16* __restrict__ src, int stride,
                                          int t, s16x8* ld)
{
  #pragma unroll
  for (int i = 0; i < 2; ++i) {
    int u = t + i*512;
    ld[i] = *(const s16x8*)(src + (u >> 4)*stride + (u & 15)*8);
  }
}
__device__ __forceinline__ void ldw_write(u8* __restrict__ smem_, int p, int t, const s16x8* ld)
{
  #pragma unroll
  for (int i = 0; i < 2; ++i) {
    int u = t + i*512;
    *(s16x8*)(smem_ + WBo(p) + WIDX(u >> 4, (u & 15)*16)) = ld[i];
  }
}

// bfr for embed: K=16: koct0 -> obs[12a+0..7]; koct1 -> obs[12a+8..11], action, 0,0,0
__device__ __forceinline__ s16x8 make_bfr32(const float* __restrict__ xr, int a, int koct)
{
  s16x8 v = {0,0,0,0,0,0,0,0};
  if (koct == 0) {
    #pragma unroll
    for (int e = 0; e < 8; ++e) v[e] = (short)f2bf(xr[12*a + e]);
  } else {
    #pragma unroll
    for (int e = 0; e < 4; ++e) v[e] = (short)f2bf(xr[12*a + 8 + e]);
    v[4] = (short)f2bf(xr[36 + a]);
  }
  return v;
}

// embed: wave (nt, mg) computes feats mg*128..+127 (4 mt32) for cols nt*32..+31; K=16 one MFMA
__device__ __forceinline__ void embed_c32(const u8* __restrict__ wb, u8* __restrict__ act,
    const float* __restrict__ bias, s16x8 bfr, int nt, int mg, int l31, int koct)
{
  #pragma unroll
  for (int jj = 0; jj < 4; ++jj) {
    const int mt = mg*4 + jj;
    s16x8 a = *(const s16x8*)(wb + EIDX2(mt*32 + l31, koct*16));
    f32x16 acc = zero16();
    acc = MFMA32(a, bfr, acc, 0, 0, 0);
    #pragma unroll
    for (int g = 0; g < 4; ++g) {
      f32x4 bb = ((const f32x4*)bias)[mt*8 + 2*g + koct];
      s16x4 pk;
      #pragma unroll
      for (int r = 0; r < 4; ++r) pk[r] = (short)f2bf(acc[4*g + r] + bb[r]);
      *(s16x4*)(act + AIDX(nt*32 + l31, (mt*32 + 8*g + 4*koct)*2)) = pk;
    }
  }
}

// ---- pipelined attention (32x32 MFMA): e_q -> ACT_EQ, atten -> ACT_WK; returns WB parity
// chunks: c0=embA0 c1=embA1 c2..c9=V(kh=j>>2,o=j&3) pass1, c10=embA2, c11..c18 pass2, [c19,c20]
__device__ __forceinline__ int attn_run32(
    u8* __restrict__ smem, const float* __restrict__ x, int rowbase,
    const u16* __restrict__ wEmb16, const float* __restrict__ be,
    const float* __restrict__ bk1, const float* __restrict__ bk2,
    const u16* __restrict__ wV, const float* __restrict__ bv,
    const float* __restrict__ wrow,
    const u16* __restrict__ n19, int s19, const u16* __restrict__ n20, int s20,
    int t, s16x8* ld)
{
  const int lane = t & 63;
  const int l31 = lane & 31, koct = lane >> 5;
  const int wv_ = t >> 6;
  const int nt = wv_ & 3, mg = wv_ >> 2;
  const int myrow = rowbase + nt*32 + l31;
  const float w1 = wrow[myrow];
  const float* xr = x + (size_t)myrow*39;
  s16x8 bfr0 = make_bfr32(xr, 0, koct);
  s16x8 bfr1 = make_bfr32(xr, 1, koct);
  s16x8 bfr2 = make_bfr32(xr, 2, koct);

  // prologue: c0 (embA0, 8KB) -> WB0; c1 issued
  ld[0] = *(const s16x8*)(wEmb16 + t*8);
  *(s16x8*)(smem + WBo(0) + EIDX2(t >> 1, (t & 1)*16)) = ld[0];
  ld[0] = *(const s16x8*)(wEmb16 + 4096 + t*8);
  BARX();
  int p = 0;

  // c0: emb0 -> EQ (e_q)
  *(s16x8*)(smem + WBo(p^1) + EIDX2(t >> 1, (t & 1)*16)) = ld[0];
  ldw_issue(wV, 256, t, ld);                          // c2 = V(k0,o0)
  embed_c32(smem + WBo(p), smem + ACT_EQ, be, bfr0, nt, mg, l31, koct);
  BARX(); p ^= 1;

  // c1: emb1 -> WK (e_k1)
  ldw_write(smem, p^1, t, ld);
  ldw_issue(wV + 16384, 256, t, ld);                  // c3 = V(k0,o1)
  embed_c32(smem + WBo(p), smem + ACT_WK, bk1, bfr1, nt, mg, l31, koct);
  BARX(); p ^= 1;

  f32x16 accV1[4];
  #pragma unroll
  for (int o = 0; o < 4; ++o) accV1[o] = zero16();
  s16x8 bqv[8];

  // pass1: c2..c9 ; B = e_k1
  #pragma unroll
  for (int j = 0; j < 8; ++j) {
    const int kh = j >> 2, o = j & 3;
    if (o == 0) {
      #pragma unroll
      for (int ks = 0; ks < 8; ++ks)
        bqv[ks] = *(const s16x8*)(smem + ACT_WK + AIDX(nt*32 + l31, kh*256 + ks*32 + koct*16));
    }
    if (j < 7) ldw_write(smem, p^1, t, ld);
    else       *(s16x8*)(smem + WBo(p^1) + EIDX2(t >> 1, (t & 1)*16)) = ld[0];  // c10=embA2
    if (j < 6)      { const int i2 = j + 2; ldw_issue(wV + (i2&3)*16384 + (i2>>2)*128, 256, t, ld); }
    else if (j == 6) ld[0] = *(const s16x8*)(wEmb16 + 8192 + t*8);              // c10
    else             ldw_issue(wV, 256, t, ld);                                 // c11
    #pragma unroll
    for (int ks = 0; ks < 8; ++ks) {
      s16x8 a = *(const s16x8*)(smem + WBo(p) + WIDX(mg*32 + l31, ks*32 + koct*16));
      accV1[o] = MFMA32(a, bqv[ks], accV1[o], 0, 0, 0);
    }
    BARX(); p ^= 1;
  }

  // c10: emb2 -> WK (e_k2)
  ldw_write(smem, p^1, t, ld);                        // c11
  ldw_issue(wV + 16384, 256, t, ld);                  // c12
  embed_c32(smem + WBo(p), smem + ACT_WK, bk2, bfr2, nt, mg, l31, koct);
  BARX(); p ^= 1;

  f32x16 accV2[4];
  #pragma unroll
  for (int o = 0; o < 4; ++o) accV2[o] = zero16();

  // pass2: c11..c18 ; B = e_k2; combine + atten at end
  #pragma unroll
  for (int j = 0; j < 8; ++j) {
    const int kh = j >> 2, o = j & 3;
    if (o == 0) {
      #pragma unroll
      for (int ks = 0; ks < 8; ++ks)
        bqv[ks] = *(const s16x8*)(smem + ACT_WK + AIDX(nt*32 + l31, kh*256 + ks*32 + koct*16));
    }
    if (j < 7)       ldw_write(smem, p^1, t, ld);
    else if (n19)    ldw_write(smem, p^1, t, ld);     // c19
    if (j < 6)       { const int i2 = j + 2; ldw_issue(wV + (i2&3)*16384 + (i2>>2)*128, 256, t, ld); }
    else if (j == 6) { if (n19) ldw_issue(n19, s19, t, ld); }
    else             { if (n20) ldw_issue(n20, s20, t, ld); }
    #pragma unroll
    for (int ks = 0; ks < 8; ++ks) {
      s16x8 a = *(const s16x8*)(smem + WBo(p) + WIDX(mg*32 + l31, ks*32 + koct*16));
      accV2[o] = MFMA32(a, bqv[ks], accV2[o], 0, 0, 0);
    }
    if (j == 7) {
      const float w2 = 1.f - w1;
      #pragma unroll
      for (int o2 = 0; o2 < 4; ++o2)
        #pragma unroll
        for (int g = 0; g < 4; ++g) {
          f32x4 bb = ((const f32x4*)bv)[o2*16 + mg*8 + 2*g + koct];
          s16x4 pk;
          #pragma unroll
          for (int r = 0; r < 4; ++r) {
            float va = accV1[o2][4*g + r] + bb[r]; va = (va > 0.f) ? va : 0.01f*va;
            float vb = accV2[o2][4*g + r] + bb[r]; vb = (vb > 0.f) ? vb : 0.01f*vb;
            pk[r] = (short)f2bf(w1*va + w2*vb);
          }
          *(s16x4*)(smem + ACT_WK + AIDX(nt*32 + l31, (o2*64 + mg*32 + 8*g + 4*koct)*2)) = pk;
        }
    }
    BARX(); p ^= 1;
  }
  return p;
}

// ---------------- K1: attention -> BN partial sums ----------------
__global__ __launch_bounds__(512) __attribute__((amdgpu_waves_per_eu(1, 2)))
void k1_attn(
    const float* __restrict__ x,
    const u16* __restrict__ wEmb16, const float* __restrict__ be,
    const float* __restrict__ bk1, const float* __restrict__ bk2,
    const u16* __restrict__ wV, const float* __restrict__ bv,
    const float* __restrict__ wrow,
    float* __restrict__ pA, float* __restrict__ pB)
{
  __shared__ __align__(16) u8 smem[SMEM_BYTES];
  const int t = threadIdx.x;
  const int wt = blockIdx.x;
  const int rowbase = wt * 128;
  s16x8 ld[2];

  attn_run32(smem, x, rowbase, wEmb16, be, bk1, bk2, wV, bv, wrow,
             nullptr, 0, nullptr, 0, t, ld);

  // stats: thread t = (fg = t&63 feat-octet, cb = t>>6 col-block of 16)
  const int fg = t & 63, cb = t >> 6;
  const u8* rg = smem + ((fg & 32) ? ACT_WK : ACT_EQ);
  const int fb = (fg & 31) * 16;
  float s[8], q[8];
  #pragma unroll
  for (int e = 0; e < 8; ++e) { s[e] = 0.f; q[e] = 0.f; }
  #pragma unroll 4
  for (int c = 0; c < 16; ++c) {
    int col = cb*16 + c;
    u32x4 v = *(const u32x4*)(rg + AIDX(col, fb));
    #pragma unroll
    for (int j = 0; j < 4; ++j) {
      float a = bf2f((u16)(v[j] & 0xFFFFu));
      float b = bf2f((u16)(v[j] >> 16));
      s[2*j] += a; q[2*j] += a*a;
      s[2*j+1] += b; q[2*j+1] += b*b;
    }
  }
  float* sb = (float*)(smem + WB0_OFF);
  #pragma unroll
  for (int e = 0; e < 8; ++e) {
    sb[(fg*8 + e)*8 + cb]        = s[e];
    sb[4096 + (fg*8 + e)*8 + cb] = q[e];
  }
  __syncthreads();
  {
    int f = t;
    float ss = 0.f, qs = 0.f;
    #pragma unroll
    for (int c2 = 0; c2 < 8; ++c2) { ss += sb[f*8 + c2]; qs += sb[4096 + f*8 + c2]; }
    pA[(size_t)wt*512 + f] = ss;
    pB[(size_t)wt*512 + f] = qs;
  }
}

// ---------------- KR1 / KR2 / K2b ----------------
__global__ void kR1_reduce(const float* __restrict__ pA, const float* __restrict__ pB,
                           float* __restrict__ qA, float* __restrict__ qB)
{
  int g = blockIdx.x, t = threadIdx.x;   // 256 x 256
  float2 sA = make_float2(0.f, 0.f), sB = make_float2(0.f, 0.f);
  #pragma unroll
  for (int k = 0; k < 8; ++k) {
    size_t wg = (size_t)g*8 + k;
    float2 a = *(const float2*)(pA + wg*512 + 2*t);
    float2 b = *(const float2*)(pB + wg*512 + 2*t);
    sA.x += a.x; sA.y += a.y; sB.x += b.x; sB.y += b.y;
  }
  *(float2*)(qA + (size_t)g*512 + 2*t) = sA;
  *(float2*)(qB + (size_t)g*512 + 2*t) = sB;
}

__global__ void kR2_stats(const float* __restrict__ qA, const float* __restrict__ qB,
                          float* __restrict__ mu, float* __restrict__ rstd)
{
  int f = blockIdx.x, t = threadIdx.x;   // 512 x 256
  float s = qA[(size_t)t*512 + f];
  float q = qB[(size_t)t*512 + f];
  #pragma unroll
  for (int off = 1; off < 64; off <<= 1) {
    s += __shfl_xor(s, off);
    q += __shfl_xor(q, off);
  }
  __shared__ float ls[4], lq[4];
  if ((t & 63) == 0) { ls[t >> 6] = s; lq[t >> 6] = q; }
  __syncthreads();
  if (t == 0) {
    float S = ls[0]+ls[1]+ls[2]+ls[3];
    float Q = lq[0]+lq[1]+lq[2]+lq[3];
    float m = S * (1.f/262144.f);
    float v = Q * (1.f/262144.f) - m*m;
    mu[f] = m;
    rstd[f] = 1.f / sqrtf(v + 1e-5f);
  }
}

__global__ void k2b_fold(const float* __restrict__ W1, const float* __restrict__ b1,
                         const float* __restrict__ mu, const float* __restrict__ rstd,
                         u16* __restrict__ W1s, float* __restrict__ b1eff)
{
  int o = blockIdx.x, t = threadIdx.x;
  float local = 0.f;
  #pragma unroll
  for (int k = 0; k < 2; ++k) {
    int f = t + k*256;
    float w = W1[o*512 + f];
    float r = rstd[f];
    W1s[o*512 + f] = f2bf(w * r);
    local += w * r * mu[f];
  }
  #pragma unroll
  for (int off = 1; off < 64; off <<= 1) local += __shfl_xor(local, off);
  __shared__ float ls[4];
  if ((t & 63) == 0) ls[t >> 6] = local;
  __syncthreads();
  if (t == 0) b1eff[o] = b1[o] - (ls[0]+ls[1]+ls[2]+ls[3]);
}

// ---------------- K3: attention recompute + MLP ----------------
__global__ __launch_bounds__(512) __attribute__((amdgpu_waves_per_eu(1, 2)))
void k3_mlp(
    const float* __restrict__ x,
    const u16* __restrict__ wEmb16, const float* __restrict__ be,
    const float* __restrict__ bk1, const float* __restrict__ bk2,
    const u16* __restrict__ wV, const float* __restrict__ bv,
    const float* __restrict__ wrow,
    const u16* __restrict__ W1s, const float* __restrict__ b1eff,
    const u16* __restrict__ wW2, const float* __restrict__ b2,
    const float* __restrict__ W3, const float* __restrict__ b3,
    float* __restrict__ out)
{
  __shared__ __align__(16) u8 smem[SMEM_BYTES];
  const int t = threadIdx.x;
  const int wt = blockIdx.x;
  const int rowbase = wt * 128;
  const int lane = t & 63;
  const int l31 = lane & 31, koct = lane >> 5;
  const int wv_ = t >> 6;
  const int ng = wv_ & 3, mgw = wv_ >> 2;
  s16x8 ld[2];

  int p = attn_run32(smem, x, rowbase, wEmb16, be, bk1, bk2, wV, bv, wrow,
                     W1s, 512, W1s + 32768, 512, t, ld);
  // WB[p] = W1s(q0,o0), ld = W1s(q0,o1)

  // GEMM1: c19..c34 = W1s(q=i>>2, o=i&3); B: q0,q1 = e_q (EQ), q2,q3 = atten (WK)
  f32x16 acc1[4];
  #pragma unroll
  for (int o = 0; o < 4; ++o) acc1[o] = zero16();
  s16x8 bq[8];

  #pragma unroll
  for (int i = 0; i < 16; ++i) {
    const int q = i >> 2, o = i & 3;
    if (o == 0) {
      const int areg = (q < 2) ? ACT_EQ : ACT_WK;
      const int qb = (q & 1) * 256;
      #pragma unroll
      for (int ks = 0; ks < 8; ++ks)
        bq[ks] = *(const s16x8*)(smem + areg + AIDX(ng*32 + l31, qb + ks*32 + koct*16));
    }
    ldw_write(smem, p^1, t, ld);
    if (i < 14) { const int j = i + 2; ldw_issue(W1s + (size_t)(j&3)*32768 + (j>>2)*128, 512, t, ld); }
    else        { const int j = i - 14; ldw_issue(wW2 + (size_t)(j&1)*16384 + (j>>1)*128, 256, t, ld); }
    #pragma unroll
    for (int ks = 0; ks < 8; ++ks) {
      s16x8 a = *(const s16x8*)(smem + WBo(p) + WIDX(mgw*32 + l31, ks*32 + koct*16));
      acc1[o] = MFMA32(a, bq[ks], acc1[o], 0, 0, 0);
    }
    if (i == 15) {
      // h1 = relu(acc1 + b1eff) -> ACT_EQ (e_q last read at q1 hoist)
      #pragma unroll
      for (int o2 = 0; o2 < 4; ++o2)
        #pragma unroll
        for (int g = 0; g < 4; ++g) {
          f32x4 bb = ((const f32x4*)b1eff)[o2*16 + mgw*8 + 2*g + koct];
          s16x4 pk;
          #pragma unroll
          for (int r = 0; r < 4; ++r) {
            float v = acc1[o2][4*g + r] + bb[r];
            pk[r] = (short)f2bf((v > 0.f) ? v : 0.f);
          }
          *(s16x4*)(smem + ACT_EQ + AIDX(ng*32 + l31, (o2*64 + mgw*32 + 8*g + 4*koct)*2)) = pk;
        }
    }
    BARX(); p ^= 1;
  }

  // GEMM2: c35..c38 = W2(q=i>>1, o=i&1); B = h1 (EQ)
  f32x16 acc2[2];
  #pragma unroll
  for (int o = 0; o < 2; ++o) acc2[o] = zero16();

  #pragma unroll
  for (int i = 0; i < 4; ++i) {
    const int q = i >> 1, o = i & 1;
    if (o == 0) {
      const int qb = q * 256;
      #pragma unroll
      for (int ks = 0; ks < 8; ++ks)
        bq[ks] = *(const s16x8*)(smem + ACT_EQ + AIDX(ng*32 + l31, qb + ks*32 + koct*16));
    }
    if (i < 3) ldw_write(smem, p^1, t, ld);
    if (i < 2) { const int j = i + 2; ldw_issue(wW2 + (size_t)(j&1)*16384 + (j>>1)*128, 256, t, ld); }
    #pragma unroll
    for (int ks = 0; ks < 8; ++ks) {
      s16x8 a = *(const s16x8*)(smem + WBo(p) + WIDX(mgw*32 + l31, ks*32 + koct*16));
      acc2[o] = MFMA32(a, bq[ks], acc2[o], 0, 0, 0);
    }
    if (i == 3) {
      // h2 = relu(acc2 + b2) -> ACT_WK (atten last read at q3 hoist)
      #pragma unroll
      for (int o2 = 0; o2 < 2; ++o2)
        #pragma unroll
        for (int g = 0; g < 4; ++g) {
          f32x4 bb = ((const f32x4*)b2)[o2*16 + mgw*8 + 2*g + koct];
          s16x4 pk;
          #pragma unroll
          for (int r = 0; r < 4; ++r) {
            float v = acc2[o2][4*g + r] + bb[r];
            pk[r] = (short)f2bf((v > 0.f) ? v : 0.f);
          }
          *(s16x4*)(smem + ACT_WK + AIDX(ng*32 + l31, (o2*64 + mgw*32 + 8*g + 4*koct)*2)) = pk;
        }
    }
    BARX(); p ^= 1;
  }

  // out = W3 . h2 + b3 (one thread per row)
  if (t < 128) {
    float s = b3[0];
    #pragma unroll
    for (int jj = 0; jj < 16; ++jj) {
      const u32x4 v = *(const u32x4*)(smem + ACT_WK + AIDX(t, jj*16));
      #pragma unroll
      for (int q2 = 0; q2 < 4; ++q2) {
        u32 u = v[q2];
        s += bf2f((u16)(u & 0xFFFFu)) * W3[jj*8 + q2*2];
        s += bf2f((u16)(u >> 16))     * W3[jj*8 + q2*2 + 1];
      }
    }
    out[rowbase + t] = s;
  }
}

extern "C" void kernel_launch(void* const* d_in, const int* in_sizes, int n_in,
                              void* d_out, int out_size, void* d_ws, size_t ws_size,
                              hipStream_t stream)
{
  const float* x   = (const float*)d_in[0];
  const float* We  = (const float*)d_in[1];
  const float* be  = (const float*)d_in[2];
  const float* Wk1 = (const float*)d_in[3];
  const float* bk1 = (const float*)d_in[4];
  const float* Wk2 = (const float*)d_in[5];
  const float* bk2 = (const float*)d_in[6];
  const float* Wq  = (const float*)d_in[7];
  const float* Wk  = (const float*)d_in[8];
  const float* Wv  = (const float*)d_in[9];
  const float* bv  = (const float*)d_in[10];
  const float* W1  = (const float*)d_in[11];
  const float* b1  = (const float*)d_in[12];
  const float* W2  = (const float*)d_in[13];
  const float* b2  = (const float*)d_in[14];
  const float* W3  = (const float*)d_in[15];
  const float* b3  = (const float*)d_in[16];

  u8* ws = (u8*)d_ws;
  float* pA    = (float*)(ws + PA_OFF);
  float* pB    = (float*)(ws + PB_OFF);
  float* qA    = (float*)(ws + QA_OFF);
  float* qB    = (float*)(ws + QB_OFF);
  float* mu    = (float*)(ws + MU_OFF);
  float* rstd  = (float*)(ws + RSTD_OFF);
  float* b1eff = (float*)(ws + B1E_OFF);
  u16*   wEmb  = (u16*)(ws + WEMB_OFF);
  u16*   wVb   = (u16*)(ws + WV_OFF);
  u16*   wW2   = (u16*)(ws + W2_OFF);
  u16*   wW1s  = (u16*)(ws + W1S_OFF);
  float* Wu    = (float*)(ws + WU_OFF);
  float* G     = (float*)(ws + G_OFF);
  float* g     = (float*)(ws + GG_OFF);
  float* scp   = (float*)(ws + SCP_OFF);
  float* wrow  = (float*)(ws + WROW_OFF);

  k0_convert<<<dim3(432), dim3(256), 0, stream>>>(We, Wk1, Wk2, Wv, W2, wEmb, wVb, wW2);
  k0b_wu<<<dim3(256), dim3(256), 0, stream>>>(Wq, Wk, Wu);
  k0c_G<<<dim3(2), dim3(256), 0, stream>>>(Wu, Wk1, bk1, Wk2, bk2, G, g);
  k0d_M<<<dim3(2), dim3(256), 0, stream>>>(We, be, G, g, scp);
  k0e_scores<<<dim3(1024), dim3(256), 0, stream>>>(x, scp, wrow);
  k1_attn<<<dim3(NTILE), dim3(512), 0, stream>>>(x, wEmb, be, bk1, bk2, wVb, bv, wrow, pA, pB);
  kR1_reduce<<<dim3(256), dim3(256), 0, stream>>>(pA, pB, qA, qB);
  kR2_stats<<<dim3(512), dim3(256), 0, stream>>>(qA, qB, mu, rstd);
  k2b_fold<<<dim3(256), dim3(256), 0, stream>>>(W1, b1, mu, rstd, wW1s, b1eff);
  k3_mlp<<<dim3(NTILE), dim3(512), 0, stream>>>(x, wEmb, be, bk1, bk2, wVb, bv, wrow,
                                                wW1s, b1eff, wW2, b2, W3, b3,
                                                (float*)d_out);
}

// Round 11
// 416.337 us; speedup vs baseline: 1.7425x; 1.1893x over previous
//
#include <hip/hip_runtime.h>
#include <cstdint>
#include <cstddef>

typedef unsigned char  u8;
typedef unsigned short u16;
typedef unsigned int   u32;

typedef __attribute__((ext_vector_type(8)))  short s16x8;
typedef __attribute__((ext_vector_type(4)))  short s16x4;
typedef __attribute__((ext_vector_type(4)))  float f32x4;
typedef __attribute__((ext_vector_type(16))) float f32x16;
typedef __attribute__((ext_vector_type(4)))  u32   u32x4;

#define NTILE 2048   // 262144 / 128 rows per tile

// LDS: ACT_EQ 64KB + ACT_WK 64KB + WB 2x16KB = 160KB
#define ACT_EQ 0
#define ACT_WK 65536
#define WB0_OFF 131072
#define WBSZ    16384
#define SMEM_BYTES 163840
#define WBo(p) (WB0_OFF + (p)*WBSZ)

// XOR-swizzled layouts
#define AIDX(col, fb)  ((((col)*512) + (fb)) ^ (((col)&7) << 4))   // act [128 col][512B]
#define WIDX(row, kb)  ((((row)*256) + (kb)) ^ (((row)&7) << 4))   // wchunk [64 row][256B]
#define EIDX2(row, kb) ((((row)*32)  + (kb)) ^ ((((row)>>2)&1) << 4)) // emb16 [256 row][32B]

#define MFMA32 __builtin_amdgcn_mfma_f32_32x32x16_bf16

// raw barrier: LDS visibility without draining vmem (prefetch survives)
#define BARX() do { __builtin_amdgcn_sched_barrier(0); \
  asm volatile("s_waitcnt lgkmcnt(0)"); \
  __builtin_amdgcn_s_barrier(); \
  __builtin_amdgcn_sched_barrier(0); } while (0)

// ---------------- workspace layout (bytes) ----------------
static const size_t PA_OFF   = 0;          // f32 [2048 tile][512 f]
static const size_t PB_OFF   = 4194304;
static const size_t QA_OFF   = 8388608;    // f32 [256 g][512 f]
static const size_t QB_OFF   = 8912896;
static const size_t MU_OFF   = 9437184;
static const size_t RSTD_OFF = 9439232;
static const size_t B1E_OFF  = 9441280;
static const size_t WEMB_OFF = 9442304;    // bf16 [3][256][16]
static const size_t WV_OFF   = 9491456;    // bf16 [256][256]
static const size_t W2_OFF   = 9622528;    // bf16 [128][256]
static const size_t W1S_OFF  = 9688064;    // bf16 [256][512]
static const size_t WU_OFF   = 9950208;    // f32 [256][256]
static const size_t G_OFF    = 10212352;   // f32 [2][256][13]
static const size_t GG_OFF   = 10238976;   // f32 [2][256]
static const size_t SCP_OFF  = 10241024;   // f32 [2][256]
static const size_t WROW_OFF = 10243072;   // f32 [262144]
// base end = 11291648
static const size_t XA_OFF   = 11534336;   // pre-swizzled atten tiles [2048][65536B]
static const size_t WS_NEED_X = XA_OFF + (size_t)2048*65536;   // 145,752,064

__device__ __forceinline__ u16 f2bf(float f) {
  u32 u = __builtin_bit_cast(u32, f);
  u += 0x7FFFu + ((u >> 16) & 1u);     // RNE
  return (u16)(u >> 16);
}
__device__ __forceinline__ float bf2f(u16 h) {
  u32 u = ((u32)h) << 16;
  return __builtin_bit_cast(float, u);
}
__device__ __forceinline__ f32x16 zero16() {
  f32x16 z;
  #pragma unroll
  for (int i = 0; i < 16; ++i) z[i] = 0.f;
  return z;
}

// ---------------- K0 setup kernels ----------------
__global__ void k0_convert(const float* __restrict__ We,  const float* __restrict__ Wk1,
                           const float* __restrict__ Wk2, const float* __restrict__ Wv,
                           const float* __restrict__ W2,
                           u16* __restrict__ wEmb, u16* __restrict__ wV, u16* __restrict__ wW2)
{
  int i = blockIdx.x * 256 + threadIdx.x;
  if (i < 12288) {                          // emb16 [agent][256][16]
    int which = i >> 12, rem = i & 4095, h = rem >> 4, c = rem & 15;
    const float* W = (which == 0) ? We : (which == 1) ? Wk1 : Wk2;
    wEmb[i] = (c < 13) ? f2bf(W[h*13 + c]) : (u16)0;
  } else if (i < 12288 + 65536) {
    int j = i - 12288;
    wV[j] = f2bf(Wv[j]);
  } else if (i < 12288 + 65536 + 32768) {
    int j = i - 77824;
    wW2[j] = f2bf(W2[j]);
  }
}

__global__ void k0b_wu(const float* __restrict__ Wq, const float* __restrict__ Wk,
                       float* __restrict__ Wu)
{
  int a = blockIdx.x, b = threadIdx.x;
  float acc = 0.f;
  #pragma unroll 4
  for (int h = 0; h < 256; ++h)
    acc += Wq[h*256 + a] * Wk[h*256 + b];
  Wu[a*256 + b] = acc;
}

__global__ void k0c_G(const float* __restrict__ Wu,
                      const float* __restrict__ Wk1, const float* __restrict__ bk1,
                      const float* __restrict__ Wk2, const float* __restrict__ bk2,
                      float* __restrict__ G, float* __restrict__ g)
{
  int j = blockIdx.x, a = threadIdx.x;
  const float* Wkj = j ? Wk2 : Wk1;
  const float* bkj = j ? bk2 : bk1;
  float acc[13];
  #pragma unroll
  for (int q = 0; q < 13; ++q) acc[q] = 0.f;
  float ga = 0.f;
  for (int b = 0; b < 256; ++b) {
    float wu = Wu[a*256 + b];
    #pragma unroll
    for (int q = 0; q < 13; ++q) acc[q] += wu * Wkj[b*13 + q];
    ga += wu * bkj[b];
  }
  #pragma unroll
  for (int q = 0; q < 13; ++q) G[j*3328 + a*13 + q] = acc[q];
  g[j*256 + a] = ga;
}

__global__ void k0d_M(const float* __restrict__ We, const float* __restrict__ be,
                      const float* __restrict__ G, const float* __restrict__ g,
                      float* __restrict__ scp)
{
  int j = blockIdx.x, t = threadIdx.x;
  float acc = 0.f;
  if (t < 169) {
    int p = t / 13, q = t - p*13;
    for (int a = 0; a < 256; ++a) acc += We[a*13 + p] * G[j*3328 + a*13 + q];
    scp[j*256 + t] = acc;
  } else if (t < 182) {
    int p = t - 169;
    for (int a = 0; a < 256; ++a) acc += We[a*13 + p] * g[j*256 + a];
    scp[j*256 + t] = acc;
  } else if (t < 195) {
    int q = t - 182;
    for (int a = 0; a < 256; ++a) acc += be[a] * G[j*3328 + a*13 + q];
    scp[j*256 + t] = acc;
  } else if (t == 195) {
    for (int a = 0; a < 256; ++a) acc += be[a] * g[j*256 + a];
    scp[j*256 + 195] = acc;
  }
}

__global__ __launch_bounds__(256) void k0e_scores(const float* __restrict__ x,
                                                  const float* __restrict__ scp,
                                                  float* __restrict__ wrow)
{
  int row = blockIdx.x * 256 + threadIdx.x;
  const float* xr = x + (size_t)row*39;
  float f0[13], f1[13], f2[13];
  #pragma unroll
  for (int p = 0; p < 12; ++p) { f0[p] = xr[p]; f1[p] = xr[12+p]; f2[p] = xr[24+p]; }
  f0[12] = xr[36]; f1[12] = xr[37]; f2[12] = xr[38];

  auto score = [&](const float* __restrict__ P, const float (&fj)[13]) -> float {
    float s = P[195];
    #pragma unroll
    for (int p = 0; p < 13; ++p) {
      float tp = P[169 + p];
      #pragma unroll
      for (int q = 0; q < 13; ++q) tp += P[p*13 + q] * fj[q];
      s += f0[p] * tp;
    }
    #pragma unroll
    for (int q = 0; q < 13; ++q) s += P[182 + q] * fj[q];
    return s;
  };
  float s1 = score(scp, f1);
  float s2 = score(scp + 256, f2);
  wrow[row] = 1.f / (1.f + __expf((s2 - s1) * 0.0625f));   // /sqrt(256)
}

// ---------------- staging (512 threads) ----------------
__device__ __forceinline__ void ldw_issue(const u16* __restrict__ src, int stride,
                                          int t, s16x8* ld)
{
  #pragma unroll
  for (int i = 0; i < 2; ++i) {
    int u = t + i*512;
    ld[i] = *(const s16x8*)(src + (u >> 4)*stride + (u & 15)*8);
  }
}
__device__ __forceinline__ void ldw_write(u8* __restrict__ smem_, int p, int t, const s16x8* ld)
{
  #pragma unroll
  for (int i = 0; i < 2; ++i) {
    int u = t + i*512;
    *(s16x8*)(smem_ + WBo(p) + WIDX(u >> 4, (u & 15)*16)) = ld[i];
  }
}

// bfr for embed: K=16: koct0 -> obs[12a+0..7]; koct1 -> obs[12a+8..11], action, 0,0,0
__device__ __forceinline__ s16x8 make_bfr32(const float* __restrict__ xr, int a, int koct)
{
  s16x8 v = {0,0,0,0,0,0,0,0};
  if (koct == 0) {
    #pragma unroll
    for (int e = 0; e < 8; ++e) v[e] = (short)f2bf(xr[12*a + e]);
  } else {
    #pragma unroll
    for (int e = 0; e < 4; ++e) v[e] = (short)f2bf(xr[12*a + 8 + e]);
    v[4] = (short)f2bf(xr[36 + a]);
  }
  return v;
}

// embed: wave (nt, mg) computes feats mg*128..+127 (4 mt32) for cols nt*32..+31; K=16
__device__ __forceinline__ void embed_c32(const u8* __restrict__ wb, u8* __restrict__ act,
    const float* __restrict__ bias, s16x8 bfr, int nt, int mg, int l31, int koct)
{
  #pragma unroll
  for (int jj = 0; jj < 4; ++jj) {
    const int mt = mg*4 + jj;
    s16x8 a = *(const s16x8*)(wb + EIDX2(mt*32 + l31, koct*16));
    f32x16 acc = zero16();
    acc = MFMA32(a, bfr, acc, 0, 0, 0);
    #pragma unroll
    for (int g = 0; g < 4; ++g) {
      f32x4 bb = ((const f32x4*)bias)[mt*8 + 2*g + koct];
      s16x4 pk;
      #pragma unroll
      for (int r = 0; r < 4; ++r) pk[r] = (short)f2bf(acc[4*g + r] + bb[r]);
      *(s16x4*)(act + AIDX(nt*32 + l31, (mt*32 + 8*g + 4*koct)*2)) = pk;
    }
  }
}

// ---- pipelined attention (32x32 MFMA): e_q -> ACT_EQ, atten -> ACT_WK; returns WB parity
__device__ __forceinline__ int attn_run32(
    u8* __restrict__ smem, const float* __restrict__ x, int rowbase,
    const u16* __restrict__ wEmb16, const float* __restrict__ be,
    const float* __restrict__ bk1, const float* __restrict__ bk2,
    const u16* __restrict__ wV, const float* __restrict__ bv,
    const float* __restrict__ wrow,
    const u16* __restrict__ n19, int s19, const u16* __restrict__ n20, int s20,
    int t, s16x8* ld)
{
  const int lane = t & 63;
  const int l31 = lane & 31, koct = lane >> 5;
  const int wv_ = t >> 6;
  const int nt = wv_ & 3, mg = wv_ >> 2;
  const int myrow = rowbase + nt*32 + l31;
  const float w1 = wrow[myrow];
  const float* xr = x + (size_t)myrow*39;
  s16x8 bfr0 = make_bfr32(xr, 0, koct);
  s16x8 bfr1 = make_bfr32(xr, 1, koct);
  s16x8 bfr2 = make_bfr32(xr, 2, koct);

  // prologue: c0 (embA0, 8KB) -> WB0; c1 issued
  ld[0] = *(const s16x8*)(wEmb16 + t*8);
  *(s16x8*)(smem + WBo(0) + EIDX2(t >> 1, (t & 1)*16)) = ld[0];
  ld[0] = *(const s16x8*)(wEmb16 + 4096 + t*8);
  BARX();
  int p = 0;

  // c0: emb0 -> EQ (e_q)
  *(s16x8*)(smem + WBo(p^1) + EIDX2(t >> 1, (t & 1)*16)) = ld[0];
  ldw_issue(wV, 256, t, ld);                          // c2 = V(k0,o0)
  embed_c32(smem + WBo(p), smem + ACT_EQ, be, bfr0, nt, mg, l31, koct);
  BARX(); p ^= 1;

  // c1: emb1 -> WK (e_k1)
  ldw_write(smem, p^1, t, ld);
  ldw_issue(wV + 16384, 256, t, ld);                  // c3 = V(k0,o1)
  embed_c32(smem + WBo(p), smem + ACT_WK, bk1, bfr1, nt, mg, l31, koct);
  BARX(); p ^= 1;

  f32x16 accV1[4];
  #pragma unroll
  for (int o = 0; o < 4; ++o) accV1[o] = zero16();
  s16x8 bqv[8];

  // pass1: c2..c9 ; B = e_k1
  #pragma unroll
  for (int j = 0; j < 8; ++j) {
    const int kh = j >> 2, o = j & 3;
    if (o == 0) {
      #pragma unroll
      for (int ks = 0; ks < 8; ++ks)
        bqv[ks] = *(const s16x8*)(smem + ACT_WK + AIDX(nt*32 + l31, kh*256 + ks*32 + koct*16));
    }
    if (j < 7) ldw_write(smem, p^1, t, ld);
    else       *(s16x8*)(smem + WBo(p^1) + EIDX2(t >> 1, (t & 1)*16)) = ld[0];  // c10=embA2
    if (j < 6)      { const int i2 = j + 2; ldw_issue(wV + (i2&3)*16384 + (i2>>2)*128, 256, t, ld); }
    else if (j == 6) ld[0] = *(const s16x8*)(wEmb16 + 8192 + t*8);              // c10
    else             ldw_issue(wV, 256, t, ld);                                 // c11
    #pragma unroll
    for (int ks = 0; ks < 8; ++ks) {
      s16x8 a = *(const s16x8*)(smem + WBo(p) + WIDX(mg*32 + l31, ks*32 + koct*16));
      accV1[o] = MFMA32(a, bqv[ks], accV1[o], 0, 0, 0);
    }
    BARX(); p ^= 1;
  }

  // c10: emb2 -> WK (e_k2)
  ldw_write(smem, p^1, t, ld);                        // c11
  ldw_issue(wV + 16384, 256, t, ld);                  // c12
  embed_c32(smem + WBo(p), smem + ACT_WK, bk2, bfr2, nt, mg, l31, koct);
  BARX(); p ^= 1;

  f32x16 accV2[4];
  #pragma unroll
  for (int o = 0; o < 4; ++o) accV2[o] = zero16();

  // pass2: c11..c18 ; B = e_k2; combine + atten at end
  #pragma unroll
  for (int j = 0; j < 8; ++j) {
    const int kh = j >> 2, o = j & 3;
    if (o == 0) {
      #pragma unroll
      for (int ks = 0; ks < 8; ++ks)
        bqv[ks] = *(const s16x8*)(smem + ACT_WK + AIDX(nt*32 + l31, kh*256 + ks*32 + koct*16));
    }
    if (j < 7)       ldw_write(smem, p^1, t, ld);
    else if (n19)    ldw_write(smem, p^1, t, ld);     // c19
    if (j < 6)       { const int i2 = j + 2; ldw_issue(wV + (i2&3)*16384 + (i2>>2)*128, 256, t, ld); }
    else if (j == 6) { if (n19) ldw_issue(n19, s19, t, ld); }
    else             { if (n20) ldw_issue(n20, s20, t, ld); }
    #pragma unroll
    for (int ks = 0; ks < 8; ++ks) {
      s16x8 a = *(const s16x8*)(smem + WBo(p) + WIDX(mg*32 + l31, ks*32 + koct*16));
      accV2[o] = MFMA32(a, bqv[ks], accV2[o], 0, 0, 0);
    }
    if (j == 7) {
      const float w2 = 1.f - w1;
      #pragma unroll
      for (int o2 = 0; o2 < 4; ++o2)
        #pragma unroll
        for (int g = 0; g < 4; ++g) {
          f32x4 bb = ((const f32x4*)bv)[o2*16 + mg*8 + 2*g + koct];
          s16x4 pk;
          #pragma unroll
          for (int r = 0; r < 4; ++r) {
            float va = accV1[o2][4*g + r] + bb[r]; va = (va > 0.f) ? va : 0.01f*va;
            float vb = accV2[o2][4*g + r] + bb[r]; vb = (vb > 0.f) ? vb : 0.01f*vb;
            pk[r] = (short)f2bf(w1*va + w2*vb);
          }
          *(s16x4*)(smem + ACT_WK + AIDX(nt*32 + l31, (o2*64 + mg*32 + 8*g + 4*koct)*2)) = pk;
        }
    }
    BARX(); p ^= 1;
  }
  return p;
}

// ---------------- K1: attention -> BN partial sums (+ optional X-atten store) ----------------
template<bool WRITEX>
__global__ __launch_bounds__(512) __attribute__((amdgpu_waves_per_eu(1, 2)))
void k1_attn(
    const float* __restrict__ x,
    const u16* __restrict__ wEmb16, const float* __restrict__ be,
    const float* __restrict__ bk1, const float* __restrict__ bk2,
    const u16* __restrict__ wV, const float* __restrict__ bv,
    const float* __restrict__ wrow,
    float* __restrict__ pA, float* __restrict__ pB,
    u8* __restrict__ xatt)
{
  __shared__ __align__(16) u8 smem[SMEM_BYTES];
  const int t = threadIdx.x;
  const int wt = blockIdx.x;
  const int rowbase = wt * 128;
  s16x8 ld[2];

  attn_run32(smem, x, rowbase, wEmb16, be, bk1, bk2, wV, bv, wrow,
             nullptr, 0, nullptr, 0, t, ld);

  if (WRITEX) {
    u8* dst = xatt + (size_t)wt*65536;
    #pragma unroll
    for (int j = 0; j < 8; ++j)
      *(u32x4*)(dst + j*8192 + t*16) = *(const u32x4*)(smem + ACT_WK + j*8192 + t*16);
  }

  // stats: thread t = (fg = t&63 feat-octet, cb = t>>6 col-block of 16)
  const int fg = t & 63, cb = t >> 6;
  const u8* rg = smem + ((fg & 32) ? ACT_WK : ACT_EQ);
  const int fb = (fg & 31) * 16;
  float s[8], q[8];
  #pragma unroll
  for (int e = 0; e < 8; ++e) { s[e] = 0.f; q[e] = 0.f; }
  #pragma unroll 4
  for (int c = 0; c < 16; ++c) {
    int col = cb*16 + c;
    u32x4 v = *(const u32x4*)(rg + AIDX(col, fb));
    #pragma unroll
    for (int j = 0; j < 4; ++j) {
      float a = bf2f((u16)(v[j] & 0xFFFFu));
      float b = bf2f((u16)(v[j] >> 16));
      s[2*j] += a; q[2*j] += a*a;
      s[2*j+1] += b; q[2*j+1] += b*b;
    }
  }
  float* sb = (float*)(smem + WB0_OFF);
  #pragma unroll
  for (int e = 0; e < 8; ++e) {
    sb[(fg*8 + e)*8 + cb]        = s[e];
    sb[4096 + (fg*8 + e)*8 + cb] = q[e];
  }
  __syncthreads();
  {
    int f = t;
    float ss = 0.f, qs = 0.f;
    #pragma unroll
    for (int c2 = 0; c2 < 8; ++c2) { ss += sb[f*8 + c2]; qs += sb[4096 + f*8 + c2]; }
    pA[(size_t)wt*512 + f] = ss;
    pB[(size_t)wt*512 + f] = qs;
  }
}

// ---------------- KR1 / KR2 / K2b ----------------
__global__ void kR1_reduce(const float* __restrict__ pA, const float* __restrict__ pB,
                           float* __restrict__ qA, float* __restrict__ qB)
{
  int g = blockIdx.x, t = threadIdx.x;   // 256 x 256
  float2 sA = make_float2(0.f, 0.f), sB = make_float2(0.f, 0.f);
  #pragma unroll
  for (int k = 0; k < 8; ++k) {
    size_t wg = (size_t)g*8 + k;
    float2 a = *(const float2*)(pA + wg*512 + 2*t);
    float2 b = *(const float2*)(pB + wg*512 + 2*t);
    sA.x += a.x; sA.y += a.y; sB.x += b.x; sB.y += b.y;
  }
  *(float2*)(qA + (size_t)g*512 + 2*t) = sA;
  *(float2*)(qB + (size_t)g*512 + 2*t) = sB;
}

__global__ void kR2_stats(const float* __restrict__ qA, const float* __restrict__ qB,
                          float* __restrict__ mu, float* __restrict__ rstd)
{
  int f = blockIdx.x, t = threadIdx.x;   // 512 x 256
  float s = qA[(size_t)t*512 + f];
  float q = qB[(size_t)t*512 + f];
  #pragma unroll
  for (int off = 1; off < 64; off <<= 1) {
    s += __shfl_xor(s, off);
    q += __shfl_xor(q, off);
  }
  __shared__ float ls[4], lq[4];
  if ((t & 63) == 0) { ls[t >> 6] = s; lq[t >> 6] = q; }
  __syncthreads();
  if (t == 0) {
    float S = ls[0]+ls[1]+ls[2]+ls[3];
    float Q = lq[0]+lq[1]+lq[2]+lq[3];
    float m = S * (1.f/262144.f);
    float v = Q * (1.f/262144.f) - m*m;
    mu[f] = m;
    rstd[f] = 1.f / sqrtf(v + 1e-5f);
  }
}

__global__ void k2b_fold(const float* __restrict__ W1, const float* __restrict__ b1,
                         const float* __restrict__ mu, const float* __restrict__ rstd,
                         u16* __restrict__ W1s, float* __restrict__ b1eff)
{
  int o = blockIdx.x, t = threadIdx.x;
  float local = 0.f;
  #pragma unroll
  for (int k = 0; k < 2; ++k) {
    int f = t + k*256;
    float w = W1[o*512 + f];
    float r = rstd[f];
    W1s[o*512 + f] = f2bf(w * r);
    local += w * r * mu[f];
  }
  #pragma unroll
  for (int off = 1; off < 64; off <<= 1) local += __shfl_xor(local, off);
  __shared__ float ls[4];
  if ((t & 63) == 0) ls[t >> 6] = local;
  __syncthreads();
  if (t == 0) b1eff[o] = b1[o] - (ls[0]+ls[1]+ls[2]+ls[3]);
}

// ---------------- K3: MLP (attention from X-cache or recompute) ----------------
template<bool USEX>
__global__ __launch_bounds__(512) __attribute__((amdgpu_waves_per_eu(1, 2)))
void k3_mlp(
    const float* __restrict__ x,
    const u16* __restrict__ wEmb16, const float* __restrict__ be,
    const float* __restrict__ bk1, const float* __restrict__ bk2,
    const u16* __restrict__ wV, const float* __restrict__ bv,
    const float* __restrict__ wrow,
    const u16* __restrict__ W1s, const float* __restrict__ b1eff,
    const u16* __restrict__ wW2, const float* __restrict__ b2,
    const float* __restrict__ W3, const float* __restrict__ b3,
    const u8* __restrict__ xatt,
    float* __restrict__ out)
{
  __shared__ __align__(16) u8 smem[SMEM_BYTES];
  const int t = threadIdx.x;
  const int wt = blockIdx.x;
  const int rowbase = wt * 128;
  const int lane = t & 63;
  const int l31 = lane & 31, koct = lane >> 5;
  const int wv_ = t >> 6;
  const int ng = wv_ & 3, mgw = wv_ >> 2;
  s16x8 ld[2];
  int p;

  if constexpr (USEX) {
    // prologue: c0 = embA0 -> WB0 ; issue c1 = W1s#0 ; then X loads (younger than c1)
    s16x8 xl[8];
    ld[0] = *(const s16x8*)(wEmb16 + t*8);
    *(s16x8*)(smem + WBo(0) + EIDX2(t >> 1, (t & 1)*16)) = ld[0];
    ldw_issue(W1s, 512, t, ld);                       // c1
    const u8* xs = xatt + (size_t)wt*65536;
    #pragma unroll
    for (int j = 0; j < 8; ++j) xl[j] = *(const s16x8*)(xs + j*8192 + t*16);
    BARX();
    p = 0;
    // P0: write c1, issue c2, compute embA0 -> EQ, write X -> ACT_WK
    ldw_write(smem, p^1, t, ld);
    ldw_issue(W1s + 32768, 512, t, ld);               // c2 = W1s#1
    {
      const float* xr = x + (size_t)(rowbase + ng*32 + l31)*39;
      embed_c32(smem + WBo(p), smem + ACT_EQ, be, make_bfr32(xr, 0, koct), ng, mgw, l31, koct);
    }
    #pragma unroll
    for (int j = 0; j < 8; ++j)
      *(s16x8*)(smem + ACT_WK + j*8192 + t*16) = xl[j];
    BARX(); p ^= 1;
  } else {
    p = attn_run32(smem, x, rowbase, wEmb16, be, bk1, bk2, wV, bv, wrow,
                   W1s, 512, W1s + 32768, 512, t, ld);
  }
  // invariant: WB[p] = W1s#0, ld = W1s#1

  // GEMM1: 16 W1s chunks (q=i>>2, o=i&3); B: q0,q1 = e_q (EQ), q2,q3 = atten (WK)
  f32x16 acc1[4];
  #pragma unroll
  for (int o = 0; o < 4; ++o) acc1[o] = zero16();
  s16x8 bq[8];

  #pragma unroll
  for (int i = 0; i < 16; ++i) {
    const int q = i >> 2, o = i & 3;
    if (o == 0) {
      const int areg = (q < 2) ? ACT_EQ : ACT_WK;
      const int qb = (q & 1) * 256;
      #pragma unroll
      for (int ks = 0; ks < 8; ++ks)
        bq[ks] = *(const s16x8*)(smem + areg + AIDX(ng*32 + l31, qb + ks*32 + koct*16));
    }
    ldw_write(smem, p^1, t, ld);
    if (i < 14) { const int j = i + 2; ldw_issue(W1s + (size_t)(j&3)*32768 + (j>>2)*128, 512, t, ld); }
    else        { const int j = i - 14; ldw_issue(wW2 + (size_t)(j&1)*16384 + (j>>1)*128, 256, t, ld); }
    #pragma unroll
    for (int ks = 0; ks < 8; ++ks) {
      s16x8 a = *(const s16x8*)(smem + WBo(p) + WIDX(mgw*32 + l31, ks*32 + koct*16));
      acc1[o] = MFMA32(a, bq[ks], acc1[o], 0, 0, 0);
    }
    if (i == 15) {
      // h1 = relu(acc1 + b1eff) -> ACT_EQ
      #pragma unroll
      for (int o2 = 0; o2 < 4; ++o2)
        #pragma unroll
        for (int g = 0; g < 4; ++g) {
          f32x4 bb = ((const f32x4*)b1eff)[o2*16 + mgw*8 + 2*g + koct];
          s16x4 pk;
          #pragma unroll
          for (int r = 0; r < 4; ++r) {
            float v = acc1[o2][4*g + r] + bb[r];
            pk[r] = (short)f2bf((v > 0.f) ? v : 0.f);
          }
          *(s16x4*)(smem + ACT_EQ + AIDX(ng*32 + l31, (o2*64 + mgw*32 + 8*g + 4*koct)*2)) = pk;
        }
    }
    BARX(); p ^= 1;
  }

  // GEMM2: 4 W2 chunks (q=i>>1, o=i&1); B = h1 (EQ)
  f32x16 acc2[2];
  #pragma unroll
  for (int o = 0; o < 2; ++o) acc2[o] = zero16();

  #pragma unroll
  for (int i = 0; i < 4; ++i) {
    const int q = i >> 1, o = i & 1;
    if (o == 0) {
      const int qb = q * 256;
      #pragma unroll
      for (int ks = 0; ks < 8; ++ks)
        bq[ks] = *(const s16x8*)(smem + ACT_EQ + AIDX(ng*32 + l31, qb + ks*32 + koct*16));
    }
    if (i < 3) ldw_write(smem, p^1, t, ld);
    if (i < 2) { const int j = i + 2; ldw_issue(wW2 + (size_t)(j&1)*16384 + (j>>1)*128, 256, t, ld); }
    #pragma unroll
    for (int ks = 0; ks < 8; ++ks) {
      s16x8 a = *(const s16x8*)(smem + WBo(p) + WIDX(mgw*32 + l31, ks*32 + koct*16));
      acc2[o] = MFMA32(a, bq[ks], acc2[o], 0, 0, 0);
    }
    if (i == 3) {
      // h2 = relu(acc2 + b2) -> ACT_WK
      #pragma unroll
      for (int o2 = 0; o2 < 2; ++o2)
        #pragma unroll
        for (int g = 0; g < 4; ++g) {
          f32x4 bb = ((const f32x4*)b2)[o2*16 + mgw*8 + 2*g + koct];
          s16x4 pk;
          #pragma unroll
          for (int r = 0; r < 4; ++r) {
            float v = acc2[o2][4*g + r] + bb[r];
            pk[r] = (short)f2bf((v > 0.f) ? v : 0.f);
          }
          *(s16x4*)(smem + ACT_WK + AIDX(ng*32 + l31, (o2*64 + mgw*32 + 8*g + 4*koct)*2)) = pk;
        }
    }
    BARX(); p ^= 1;
  }

  // out = W3 . h2 + b3 (one thread per row)
  if (t < 128) {
    float s = b3[0];
    #pragma unroll
    for (int jj = 0; jj < 16; ++jj) {
      const u32x4 v = *(const u32x4*)(smem + ACT_WK + AIDX(t, jj*16));
      #pragma unroll
      for (int q2 = 0; q2 < 4; ++q2) {
        u32 u = v[q2];
        s += bf2f((u16)(u & 0xFFFFu)) * W3[jj*8 + q2*2];
        s += bf2f((u16)(u >> 16))     * W3[jj*8 + q2*2 + 1];
      }
    }
    out[rowbase + t] = s;
  }
}

extern "C" void kernel_launch(void* const* d_in, const int* in_sizes, int n_in,
                              void* d_out, int out_size, void* d_ws, size_t ws_size,
                              hipStream_t stream)
{
  const float* x   = (const float*)d_in[0];
  const float* We  = (const float*)d_in[1];
  const float* be  = (const float*)d_in[2];
  const float* Wk1 = (const float*)d_in[3];
  const float* bk1 = (const float*)d_in[4];
  const float* Wk2 = (const float*)d_in[5];
  const float* bk2 = (const float*)d_in[6];
  const float* Wq  = (const float*)d_in[7];
  const float* Wk  = (const float*)d_in[8];
  const float* Wv  = (const float*)d_in[9];
  const float* bv  = (const float*)d_in[10];
  const float* W1  = (const float*)d_in[11];
  const float* b1  = (const float*)d_in[12];
  const float* W2  = (const float*)d_in[13];
  const float* b2  = (const float*)d_in[14];
  const float* W3  = (const float*)d_in[15];
  const float* b3  = (const float*)d_in[16];

  u8* ws = (u8*)d_ws;
  float* pA    = (float*)(ws + PA_OFF);
  float* pB    = (float*)(ws + PB_OFF);
  float* qA    = (float*)(ws + QA_OFF);
  float* qB    = (float*)(ws + QB_OFF);
  float* mu    = (float*)(ws + MU_OFF);
  float* rstd  = (float*)(ws + RSTD_OFF);
  float* b1eff = (float*)(ws + B1E_OFF);
  u16*   wEmb  = (u16*)(ws + WEMB_OFF);
  u16*   wVb   = (u16*)(ws + WV_OFF);
  u16*   wW2   = (u16*)(ws + W2_OFF);
  u16*   wW1s  = (u16*)(ws + W1S_OFF);
  float* Wu    = (float*)(ws + WU_OFF);
  float* G     = (float*)(ws + G_OFF);
  float* g     = (float*)(ws + GG_OFF);
  float* scp   = (float*)(ws + SCP_OFF);
  float* wrow  = (float*)(ws + WROW_OFF);
  u8*    xatt  = ws + XA_OFF;

  const bool useX = (ws_size >= WS_NEED_X);

  k0_convert<<<dim3(432), dim3(256), 0, stream>>>(We, Wk1, Wk2, Wv, W2, wEmb, wVb, wW2);
  k0b_wu<<<dim3(256), dim3(256), 0, stream>>>(Wq, Wk, Wu);
  k0c_G<<<dim3(2), dim3(256), 0, stream>>>(Wu, Wk1, bk1, Wk2, bk2, G, g);
  k0d_M<<<dim3(2), dim3(256), 0, stream>>>(We, be, G, g, scp);
  k0e_scores<<<dim3(1024), dim3(256), 0, stream>>>(x, scp, wrow);
  if (useX) {
    k1_attn<true><<<dim3(NTILE), dim3(512), 0, stream>>>(x, wEmb, be, bk1, bk2, wVb, bv,
                                                         wrow, pA, pB, xatt);
  } else {
    k1_attn<false><<<dim3(NTILE), dim3(512), 0, stream>>>(x, wEmb, be, bk1, bk2, wVb, bv,
                                                          wrow, pA, pB, xatt);
  }
  kR1_reduce<<<dim3(256), dim3(256), 0, stream>>>(pA, pB, qA, qB);
  kR2_stats<<<dim3(512), dim3(256), 0, stream>>>(qA, qB, mu, rstd);
  k2b_fold<<<dim3(256), dim3(256), 0, stream>>>(W1, b1, mu, rstd, wW1s, b1eff);
  if (useX) {
    k3_mlp<true><<<dim3(NTILE), dim3(512), 0, stream>>>(x, wEmb, be, bk1, bk2, wVb, bv, wrow,
                                                        wW1s, b1eff, wW2, b2, W3, b3, xatt,
                                                        (float*)d_out);
  } else {
    k3_mlp<false><<<dim3(NTILE), dim3(512), 0, stream>>>(x, wEmb, be, bk1, bk2, wVb, bv, wrow,
                                                         wW1s, b1eff, wW2, b2, W3, b3, xatt,
                                                         (float*)d_out);
  }
}